// Round 12
// baseline (164.341 us; speedup 1.0000x reference)
//
#include <hip/hip_runtime.h>
#include <math.h>

#define D  48
#define DQ 12        // D/4
#define SPAN 128     // nodes per bucket
#define SHIFT 7      // log2(SPAN)
#define PCH  8192    // edges per hist/partition block
#define PTH  512     // threads for hist/part

constexpr float F_EPS   = 1e-15f;
constexpr float MAXNORM = 1.0f - 1e-5f;

__device__ __forceinline__ float artanh_c(float x) {
    x = fminf(x, 1.0f - 1e-7f);
    x = fmaxf(x, -1.0f + 1e-7f);
    return atanhf(x);
}

__device__ __forceinline__ float clampabs(float x) {
    return (x >= 0.0f) ? fmaxf(x, 1e-10f) : fminf(x, -1e-10f);
}

__device__ __forceinline__ unsigned short f2bf(float f) {
    unsigned u = __float_as_uint(f);
    u += 0x7FFFu + ((u >> 16) & 1u);
    return (unsigned short)(u >> 16);
}

__device__ __forceinline__ float bf2f(unsigned short u) {
    return __uint_as_float(((unsigned)u) << 16);
}

// ---------- per-node gamma + zero bucket histogram ----------
__global__ void k_gamma(const float* __restrict__ x, float* __restrict__ gam,
                        int* __restrict__ ghist, int n, int nb)
{
    int i = blockIdx.x * blockDim.x + threadIdx.x;
    if (i < nb) ghist[i] = 0;
    if (i >= n) return;
    const float4* xr = reinterpret_cast<const float4*>(x) + (size_t)i * DQ;
    float s = 0.0f;
#pragma unroll
    for (int q = 0; q < DQ; ++q) {
        float4 v = xr[q];
        s += v.x * v.x + v.y * v.y + v.z * v.z + v.w * v.w;
    }
    gam[i] = 2.0f / fmaxf(1.0f - s, F_EPS);
}

// ---------- bucket histogram (LDS-staged, unrolled) ----------
__global__ __launch_bounds__(PTH) void k_hist(const int* __restrict__ dst,
                                              int* __restrict__ ghist, int E, int nb)
{
    __shared__ int h[1024];
    int t = threadIdx.x;
    for (int i = t; i < 1024; i += PTH) h[i] = 0;
    __syncthreads();
    int base = blockIdx.x * PCH;
#pragma unroll 4
    for (int k = 0; k < PCH / PTH; ++k) {
        int i = base + k * PTH + t;
        if (i < E) {
            unsigned b = ((unsigned)dst[i]) >> SHIFT;
            if (b < 1024u) atomicAdd(&h[b], 1);
        }
    }
    __syncthreads();
    for (int i = t; i < nb; i += PTH) {
        int c = h[i];
        if (c) atomicAdd(&ghist[i], c);
    }
}

// ---------- exclusive scan of bucket counts (single block, nb <= 1024) ----------
__global__ __launch_bounds__(1024) void k_scanb(const int* __restrict__ ghist,
                                                int* __restrict__ gstart,
                                                int* __restrict__ gcur, int nb, int E)
{
    __shared__ int sh[1024];
    int t = threadIdx.x;
    int v = (t < nb) ? ghist[t] : 0;
    sh[t] = v;
    __syncthreads();
    for (int off = 1; off < 1024; off <<= 1) {
        int a = sh[t];
        int b = (t >= off) ? sh[t - off] : 0;
        __syncthreads();
        sh[t] = a + b;
        __syncthreads();
    }
    if (t < nb) { int s = sh[t] - v; gstart[t] = s; gcur[t] = s; }
    if (t == 0) gstart[nb] = E;
}

// ---------- partition: bucket-burst records with packed bf16 weights ----------
__global__ __launch_bounds__(PTH) void k_part(const int* __restrict__ src,
                                              const int* __restrict__ dst,
                                              const float* __restrict__ w,
                                              const float* __restrict__ gam,
                                              int* __restrict__ gcur,
                                              int2* __restrict__ seg, int E, int nb)
{
    __shared__ int hist[1024];
    __shared__ int base_[1024];
    __shared__ int lcur[1024];
    int t = threadIdx.x;
    for (int i = t; i < 1024; i += PTH) { hist[i] = 0; base_[i] = 0; lcur[i] = 0; }
    __syncthreads();
    int b0 = blockIdx.x * PCH;
#pragma unroll 4
    for (int k = 0; k < PCH / PTH; ++k) {
        int i = b0 + k * PTH + t;
        if (i < E) {
            unsigned b = ((unsigned)dst[i]) >> SHIFT;
            if (b < 1024u) atomicAdd(&hist[b], 1);
        }
    }
    __syncthreads();
    for (int i = t; i < nb; i += PTH) {
        int c = hist[i];
        if (c) base_[i] = atomicAdd(&gcur[i], c);
    }
    __syncthreads();
#pragma unroll 4
    for (int k = 0; k < PCH / PTH; ++k) {
        int i = b0 + k * PTH + t;
        if (i < E) {
            int d = dst[i];
            unsigned b = ((unsigned)d) >> SHIFT;
            if (b < 1024u) {
                int s = src[i];
                float wv = w[i];
                float g  = gam[s];
                unsigned short wb  = f2bf(wv);
                unsigned short wdb = f2bf(fabsf(wv) * (g - 1.0f));
                int pos = base_[b] + atomicAdd(&lcur[b], 1);
                if (pos >= 0 && pos < E) {
                    int2 r;
                    r.x = ((d & (SPAN - 1)) << 24) | (s & 0xFFFFFF);
                    r.y = ((unsigned)wb << 16) | wdb;
                    seg[pos] = r;
                }
            }
        }
    }
}

// ---------- per-bucket LDS counting sort -> exact per-node order + starts ----------
__global__ __launch_bounds__(256) void k_sortb(
    const int2* __restrict__ seg, const int* __restrict__ gstart,
    int* __restrict__ starts, int2* __restrict__ seg2, int n, int E)
{
    __shared__ int hist[SPAN];
    __shared__ int sb[SPAN];
    __shared__ int cur[SPAN];
    int b = blockIdx.x;
    int t = threadIdx.x;
    if (b == 0 && t == 0) starts[n] = E;
    int segL = gstart[b], segR = gstart[b + 1];
    if (segL < 0) segL = 0;
    if (segR > E) segR = E;
    if (t < SPAN) hist[t] = 0;
    __syncthreads();
    {
        int j = segL + t;
        for (; j + 768 < segR; j += 1024) {
            unsigned d0 = ((unsigned)seg[j      ].x) >> 24;
            unsigned d1 = ((unsigned)seg[j + 256].x) >> 24;
            unsigned d2 = ((unsigned)seg[j + 512].x) >> 24;
            unsigned d3 = ((unsigned)seg[j + 768].x) >> 24;
            atomicAdd(&hist[d0], 1);
            atomicAdd(&hist[d1], 1);
            atomicAdd(&hist[d2], 1);
            atomicAdd(&hist[d3], 1);
        }
        for (; j < segR; j += 256) {
            unsigned dl = ((unsigned)seg[j].x) >> 24;
            atomicAdd(&hist[dl], 1);
        }
    }
    __syncthreads();
    if (t < SPAN) sb[t] = hist[t];
    __syncthreads();
    for (int off = 1; off < SPAN; off <<= 1) {
        int a = 0;
        if (t < SPAN) { a = sb[t]; if (t >= off) a += sb[t - off]; }
        __syncthreads();
        if (t < SPAN) sb[t] = a;
        __syncthreads();
    }
    if (t < SPAN) {
        int ls = sb[t] - hist[t];
        cur[t] = segL + ls;
        int node = b * SPAN + t;
        if (node < n) starts[node] = segL + ls;
    }
    __syncthreads();
    {
        int j = segL + t;
        for (; j + 768 < segR; j += 1024) {
            int2 r0 = seg[j      ];
            int2 r1 = seg[j + 256];
            int2 r2 = seg[j + 512];
            int2 r3 = seg[j + 768];
            int p0 = atomicAdd(&cur[((unsigned)r0.x) >> 24], 1);
            int p1 = atomicAdd(&cur[((unsigned)r1.x) >> 24], 1);
            int p2 = atomicAdd(&cur[((unsigned)r2.x) >> 24], 1);
            int p3 = atomicAdd(&cur[((unsigned)r3.x) >> 24], 1);
            if (p0 >= 0 && p0 < E) seg2[p0] = make_int2(r0.x & 0xFFFFFF, r0.y);
            if (p1 >= 0 && p1 < E) seg2[p1] = make_int2(r1.x & 0xFFFFFF, r1.y);
            if (p2 >= 0 && p2 < E) seg2[p2] = make_int2(r2.x & 0xFFFFFF, r2.y);
            if (p3 >= 0 && p3 < E) seg2[p3] = make_int2(r3.x & 0xFFFFFF, r3.y);
        }
        for (; j < segR; j += 256) {
            int2 r = seg[j];
            int pos = atomicAdd(&cur[((unsigned)r.x) >> 24], 1);
            if (pos >= 0 && pos < E) seg2[pos] = make_int2(r.x & 0xFFFFFF, r.y);
        }
    }
}

// ---------- precompute ybf[s] = bf16(gam[s] * x[s]) into dead seg buffer ----------
__global__ __launch_bounds__(256) void k_prep(const float* __restrict__ x,
                                              const float* __restrict__ gam,
                                              ushort4* __restrict__ ybf, int n)
{
    long long t = (long long)blockIdx.x * blockDim.x + threadIdx.x;
    int node = (int)(t / DQ);
    if (node >= n) return;
    int part = (int)(t % DQ);
    float g = gam[node];
    float4 v = reinterpret_cast<const float4*>(x)[(size_t)node * DQ + part];
    ushort4 o;
    o.x = f2bf(v.x * g);
    o.y = f2bf(v.y * g);
    o.z = f2bf(v.z * g);
    o.w = f2bf(v.w * g);
    ybf[(size_t)node * DQ + part] = o;
}

// ---------- gather: 12 lanes/node, single random stream, 4-wide pipeline ----------
__global__ __launch_bounds__(256) void k_gather(
    const ushort4* __restrict__ ybf,
    const int* __restrict__ starts,
    const int2* __restrict__ srec,
    float* __restrict__ num, float* __restrict__ den, int n, int E)
{
    long long t = (long long)blockIdx.x * blockDim.x + threadIdx.x;
    int node = (int)(t / DQ);
    if (node >= n) return;
    int part = (int)(t % DQ);
    int j0 = starts[node], j1 = starts[node + 1];
    if (j0 < 0) j0 = 0;
    if (j1 > E) j1 = E;
    float4 acc = make_float4(0.f, 0.f, 0.f, 0.f);
    float dacc = 0.f;
    int j = j0;
    for (; j + 3 < j1; j += 4) {
        int2 r0 = srec[j];
        int2 r1 = srec[j + 1];
        int2 r2 = srec[j + 2];
        int2 r3 = srec[j + 3];
        ushort4 a0 = ybf[(size_t)(r0.x) * DQ + part];
        ushort4 a1 = ybf[(size_t)(r1.x) * DQ + part];
        ushort4 a2 = ybf[(size_t)(r2.x) * DQ + part];
        ushort4 a3 = ybf[(size_t)(r3.x) * DQ + part];
        float w0 = bf2f((unsigned short)(((unsigned)r0.y) >> 16));
        float w1 = bf2f((unsigned short)(((unsigned)r1.y) >> 16));
        float w2 = bf2f((unsigned short)(((unsigned)r2.y) >> 16));
        float w3 = bf2f((unsigned short)(((unsigned)r3.y) >> 16));
        acc.x = fmaf(w0, bf2f(a0.x), acc.x);
        acc.y = fmaf(w0, bf2f(a0.y), acc.y);
        acc.z = fmaf(w0, bf2f(a0.z), acc.z);
        acc.w = fmaf(w0, bf2f(a0.w), acc.w);
        acc.x = fmaf(w1, bf2f(a1.x), acc.x);
        acc.y = fmaf(w1, bf2f(a1.y), acc.y);
        acc.z = fmaf(w1, bf2f(a1.z), acc.z);
        acc.w = fmaf(w1, bf2f(a1.w), acc.w);
        acc.x = fmaf(w2, bf2f(a2.x), acc.x);
        acc.y = fmaf(w2, bf2f(a2.y), acc.y);
        acc.z = fmaf(w2, bf2f(a2.z), acc.z);
        acc.w = fmaf(w2, bf2f(a2.w), acc.w);
        acc.x = fmaf(w3, bf2f(a3.x), acc.x);
        acc.y = fmaf(w3, bf2f(a3.y), acc.y);
        acc.z = fmaf(w3, bf2f(a3.z), acc.z);
        acc.w = fmaf(w3, bf2f(a3.w), acc.w);
        dacc += bf2f((unsigned short)(((unsigned)r0.y) & 0xFFFF))
              + bf2f((unsigned short)(((unsigned)r1.y) & 0xFFFF))
              + bf2f((unsigned short)(((unsigned)r2.y) & 0xFFFF))
              + bf2f((unsigned short)(((unsigned)r3.y) & 0xFFFF));
    }
    for (; j < j1; ++j) {
        int2 r0 = srec[j];
        ushort4 a0 = ybf[(size_t)(r0.x) * DQ + part];
        float w0 = bf2f((unsigned short)(((unsigned)r0.y) >> 16));
        acc.x = fmaf(w0, bf2f(a0.x), acc.x);
        acc.y = fmaf(w0, bf2f(a0.y), acc.y);
        acc.z = fmaf(w0, bf2f(a0.z), acc.z);
        acc.w = fmaf(w0, bf2f(a0.w), acc.w);
        dacc += bf2f((unsigned short)(((unsigned)r0.y) & 0xFFFF));
    }
    reinterpret_cast<float4*>(num)[(size_t)node * DQ + part] = acc;
    if (part == 0) den[node] = dacc;
}

// ---------- fallback: atomic edge scatter ----------
__global__ void k_init_atomic(float* __restrict__ den, float* __restrict__ num, int n)
{
    int i = blockIdx.x * blockDim.x + threadIdx.x;
    if (i >= n) return;
    den[i] = 0.0f;
    float4* nr = reinterpret_cast<float4*>(num) + (size_t)i * DQ;
    float4 z = make_float4(0.f, 0.f, 0.f, 0.f);
#pragma unroll
    for (int q = 0; q < DQ; ++q) nr[q] = z;
}

__global__ void k_edge_atomic(const float* __restrict__ x, const float* __restrict__ gam,
                              const int* __restrict__ src, const int* __restrict__ dst,
                              const float* __restrict__ w,
                              float* __restrict__ num, float* __restrict__ den, int E)
{
    long long t = (long long)blockIdx.x * blockDim.x + threadIdx.x;
    int e = (int)(t / DQ);
    if (e >= E) return;
    int part = (int)(t % DQ);
    int s = src[e];
    int d = dst[e];
    float we = w[e];
    float g  = gam[s];
    float4 xv = reinterpret_cast<const float4*>(x)[(size_t)s * DQ + part];
    float c = we * g;
    float* np_ = num + (size_t)d * D + part * 4;
    atomicAdd(np_ + 0, c * xv.x);
    atomicAdd(np_ + 1, c * xv.y);
    atomicAdd(np_ + 2, c * xv.z);
    atomicAdd(np_ + 3, c * xv.w);
    if (part == 0) atomicAdd(den + d, fabsf(we) * (g - 1.0f));
}

// mobius_scalar_mul(0.5, v) followed by _project, in place.
__device__ __forceinline__ void half_mul_project(float* v)
{
    float s = 0.f;
#pragma unroll
    for (int k = 0; k < D; ++k) s += v[k] * v[k];
    float nrm = sqrtf(s);
    float ncl = fmaxf(nrm, F_EPS);
    float t   = tanhf(0.5f * artanh_c(ncl));
    float sc  = t / ncl;
    float rn  = nrm * sc;
    if (rn > MAXNORM) sc *= MAXNORM / fmaxf(rn, F_EPS);
#pragma unroll
    for (int k = 0; k < D; ++k) v[k] *= sc;
}

// k_node v3: matvec output mx[] is algebraically eliminated — pass 1 computes
// only smx = ||mxraw||^2 and xyr = <mxraw, bias>; every downstream scalar
// (x2, xy, s3) is closed-form in {smx, xyr, bn2}. Pass 2 recomputes each dot
// and stores CA*acc + CB*bias[j]. Small rolled loops (no I$ thrash — R10/R11's
// 3000-instr unrolled body halved throughput), no LDS (W/bias reads are
// wave-uniform -> scalar K$ loads), no big arrays (no spill).
__global__ __launch_bounds__(256) void k_node(
    float* __restrict__ out,
    const float* __restrict__ den,
    const float* __restrict__ h_init,
    const float* __restrict__ Wm,
    const float* __restrict__ bias, int n)
{
    int i = blockIdx.x * blockDim.x + threadIdx.x;
    if (i >= n) return;

    float a[D];
    {
        const float4* nr = reinterpret_cast<const float4*>(out) + (size_t)i * DQ;
        float dinv = 1.0f / clampabs(den[i]);
#pragma unroll
        for (int q = 0; q < DQ; ++q) {
            float4 v = nr[q];
            a[q * 4 + 0] = v.x * dinv;
            a[q * 4 + 1] = v.y * dinv;
            a[q * 4 + 2] = v.z * dinv;
            a[q * 4 + 3] = v.w * dinv;
        }
    }
    half_mul_project(a);

    {
        float b[D];
        const float4* hr = reinterpret_cast<const float4*>(h_init) + (size_t)i * DQ;
#pragma unroll
        for (int q = 0; q < DQ; ++q) {
            float4 v = hr[q];
            b[q * 4 + 0] = v.x; b[q * 4 + 1] = v.y;
            b[q * 4 + 2] = v.z; b[q * 4 + 3] = v.w;
        }
        float sa = 0.f, sb = 0.f;
#pragma unroll
        for (int k = 0; k < D; ++k) { sa += a[k] * a[k]; sb += b[k] * b[k]; }
        float ga = 2.0f / fmaxf(1.0f - sa, F_EPS);
        float gb = 2.0f / fmaxf(1.0f - sb, F_EPS);
        const float wa = 0.9f, wb = 0.1f;
        float dinv = 1.0f / clampabs(wa * (ga - 1.0f) + wb * (gb - 1.0f));
        float ca = wa * ga * dinv, cb = wb * gb * dinv;
#pragma unroll
        for (int k = 0; k < D; ++k) a[k] = ca * a[k] + cb * b[k];
        half_mul_project(a);
    }

    // ---- fused mobius_matvec + mobius_add(expmap0(bias)) + project, closed form
    float sa2 = 0.f;
#pragma unroll
    for (int k = 0; k < D; ++k) sa2 += a[k] * a[k];
    float xn = fmaxf(sqrtf(sa2), F_EPS);

    float smx = 0.f, xyr = 0.f;
#pragma unroll 4
    for (int j = 0; j < D; ++j) {
        float acc = 0.f;
#pragma unroll
        for (int k = 0; k < D; ++k) acc = fmaf(Wm[j * D + k], a[k], acc);
        smx += acc * acc;
        xyr = fmaf(acc, bias[j], xyr);
    }
    float mxnr = sqrtf(smx);
    float mxn = fmaxf(mxnr, F_EPS);
    float tt = tanhf((mxn / xn) * artanh_c(xn));
    float sc = tt / mxn;
    float rn = mxnr * sc;
    if (rn > MAXNORM) sc *= MAXNORM / fmaxf(rn, F_EPS);
    // sc now includes the project factor: mx_final = sc * mxraw

    float bn2 = 0.f;
#pragma unroll
    for (int k = 0; k < D; ++k) bn2 = fmaf(bias[k], bias[k], bn2);
    float bn  = fmaxf(sqrtf(bn2), F_EPS);
    float ebs = tanhf(bn) / bn;
    float y2  = ebs * ebs * bn2;

    float x2 = sc * sc * smx;
    float xy = sc * ebs * xyr;
    float c1 = 1.0f + 2.0f * xy + y2;
    float c2 = 1.0f - x2;
    float dn3 = 1.0f / fmaxf(1.0f + 2.0f * xy + x2 * y2, F_EPS);

    float s3 = dn3 * dn3 * (c1 * c1 * sc * sc * smx
                            + 2.0f * c1 * c2 * sc * ebs * xyr
                            + c2 * c2 * ebs * ebs * bn2);
    float nrm3 = sqrtf(s3);
    float fp = (nrm3 > MAXNORM) ? (MAXNORM / fmaxf(nrm3, F_EPS)) : 1.0f;

    float CA = c1 * sc * dn3 * fp;    // multiplies mxraw_j
    float CB = c2 * ebs * dn3 * fp;   // multiplies bias_j

    float4* orow = reinterpret_cast<float4*>(out) + (size_t)i * DQ;
    for (int q = 0; q < DQ; ++q) {    // rolled: small body, recompute dots
        float e[4];
#pragma unroll
        for (int jj = 0; jj < 4; ++jj) {
            int j = q * 4 + jj;
            float acc = 0.f;
#pragma unroll
            for (int k = 0; k < D; ++k) acc = fmaf(Wm[j * D + k], a[k], acc);
            e[jj] = fmaf(CA, acc, CB * bias[j]);
        }
        float4 v;
        v.x = e[0]; v.y = e[1]; v.z = e[2]; v.w = e[3];
        orow[q] = v;
    }
}

extern "C" void kernel_launch(void* const* d_in, const int* in_sizes, int n_in,
                              void* d_out, int out_size, void* d_ws, size_t ws_size,
                              hipStream_t stream)
{
    const float* x      = (const float*)d_in[0];
    const float* h_init = (const float*)d_in[1];
    const float* edge_w = (const float*)d_in[2];
    const float* W      = (const float*)d_in[3];
    const float* bias   = (const float*)d_in[4];
    const int*   esrc   = (const int*)d_in[5];
    const int*   edst   = (const int*)d_in[6];
    float* out = (float*)d_out;

    int n = in_sizes[0] / D;
    int E = in_sizes[2];
    int nb = (n + SPAN - 1) >> SHIFT;

    // ws layout
    char* p = (char*)d_ws;
    float* gam    = (float*)p;             p += (size_t)n * 4;
    float* den    = (float*)p;             p += (size_t)n * 4;
    int*   ghist  = (int*)p;               p += (size_t)nb * 4;
    int*   gstart = (int*)p;               p += (size_t)(nb + 1) * 4;
    int*   gcur   = (int*)p;               p += (size_t)nb * 4;
    int*   starts = (int*)p;               p += (size_t)(n + 1) * 4;
    p = (char*)(((uintptr_t)p + 15) & ~(uintptr_t)15);   // align 16
    int2*  seg    = (int2*)p;              p += (size_t)E * 8;
    int2*  seg2   = (int2*)p;              p += (size_t)E * 8;
    size_t need1 = (size_t)(p - (char*)d_ws);
    ushort4* ybf = (ushort4*)seg;
    bool ybf_fits = ((size_t)E * 8 >= (size_t)n * D * 2);

    k_gamma<<<(n + 255) / 256, 256, 0, stream>>>(x, gam, ghist, n, nb);

    bool shape_ok = (nb <= 1024) && (n < (1 << 24));
    if (shape_ok && ybf_fits && need1 <= ws_size) {
        int pb = (E + PCH - 1) / PCH;
        k_hist<<<pb, PTH, 0, stream>>>(edst, ghist, E, nb);
        k_scanb<<<1, 1024, 0, stream>>>(ghist, gstart, gcur, nb, E);
        k_part<<<pb, PTH, 0, stream>>>(esrc, edst, edge_w, gam, gcur, seg, E, nb);
        k_sortb<<<nb, 256, 0, stream>>>(seg, gstart, starts, seg2, n, E);
        long long tot = (long long)n * DQ;
        int gg = (int)((tot + 255) / 256);
        k_prep<<<gg, 256, 0, stream>>>(x, gam, ybf, n);
        k_gather<<<gg, 256, 0, stream>>>(ybf, starts, seg2, out, den, n, E);
    } else {
        k_init_atomic<<<(n + 255) / 256, 256, 0, stream>>>(den, out, n);
        long long tot = (long long)E * DQ;
        k_edge_atomic<<<(int)((tot + 255) / 256), 256, 0, stream>>>(x, gam, esrc, edst, edge_w, out, den, E);
    }

    k_node<<<(n + 255) / 256, 256, 0, stream>>>(out, den, h_init, W, bias, n);
}

// Round 13
// 158.724 us; speedup vs baseline: 1.0354x; 1.0354x over previous
//
#include <hip/hip_runtime.h>
#include <math.h>

#define D  48
#define DQ 12        // D/4
#define SPAN 128     // nodes per bucket
#define SHIFT 7      // log2(SPAN)
#define PCH  8192    // edges per hist/partition block
#define PTH  512     // threads for hist/part

constexpr float F_EPS   = 1e-15f;
constexpr float MAXNORM = 1.0f - 1e-5f;

__device__ __forceinline__ float artanh_c(float x) {
    x = fminf(x, 1.0f - 1e-7f);
    x = fmaxf(x, -1.0f + 1e-7f);
    return atanhf(x);
}

__device__ __forceinline__ float clampabs(float x) {
    return (x >= 0.0f) ? fmaxf(x, 1e-10f) : fminf(x, -1e-10f);
}

__device__ __forceinline__ unsigned short f2bf(float f) {
    unsigned u = __float_as_uint(f);
    u += 0x7FFFu + ((u >> 16) & 1u);
    return (unsigned short)(u >> 16);
}

__device__ __forceinline__ float bf2f(unsigned short u) {
    return __uint_as_float(((unsigned)u) << 16);
}

// ---------- per-node gamma + zero bucket histogram ----------
__global__ void k_gamma(const float* __restrict__ x, float* __restrict__ gam,
                        int* __restrict__ ghist, int n, int nb)
{
    int i = blockIdx.x * blockDim.x + threadIdx.x;
    if (i < nb) ghist[i] = 0;
    if (i >= n) return;
    const float4* xr = reinterpret_cast<const float4*>(x) + (size_t)i * DQ;
    float s = 0.0f;
#pragma unroll
    for (int q = 0; q < DQ; ++q) {
        float4 v = xr[q];
        s += v.x * v.x + v.y * v.y + v.z * v.z + v.w * v.w;
    }
    gam[i] = 2.0f / fmaxf(1.0f - s, F_EPS);
}

// ---------- bucket histogram (LDS-staged, unrolled) ----------
__global__ __launch_bounds__(PTH) void k_hist(const int* __restrict__ dst,
                                              int* __restrict__ ghist, int E, int nb)
{
    __shared__ int h[1024];
    int t = threadIdx.x;
    for (int i = t; i < 1024; i += PTH) h[i] = 0;
    __syncthreads();
    int base = blockIdx.x * PCH;
#pragma unroll 4
    for (int k = 0; k < PCH / PTH; ++k) {
        int i = base + k * PTH + t;
        if (i < E) {
            unsigned b = ((unsigned)dst[i]) >> SHIFT;
            if (b < 1024u) atomicAdd(&h[b], 1);
        }
    }
    __syncthreads();
    for (int i = t; i < nb; i += PTH) {
        int c = h[i];
        if (c) atomicAdd(&ghist[i], c);
    }
}

// ---------- exclusive scan of bucket counts (single block, nb <= 1024) ----------
__global__ __launch_bounds__(1024) void k_scanb(const int* __restrict__ ghist,
                                                int* __restrict__ gstart,
                                                int* __restrict__ gcur, int nb, int E)
{
    __shared__ int sh[1024];
    int t = threadIdx.x;
    int v = (t < nb) ? ghist[t] : 0;
    sh[t] = v;
    __syncthreads();
    for (int off = 1; off < 1024; off <<= 1) {
        int a = sh[t];
        int b = (t >= off) ? sh[t - off] : 0;
        __syncthreads();
        sh[t] = a + b;
        __syncthreads();
    }
    if (t < nb) { int s = sh[t] - v; gstart[t] = s; gcur[t] = s; }
    if (t == 0) gstart[nb] = E;
}

// ---------- partition: bucket-burst records with packed bf16 weights ----------
__global__ __launch_bounds__(PTH) void k_part(const int* __restrict__ src,
                                              const int* __restrict__ dst,
                                              const float* __restrict__ w,
                                              const float* __restrict__ gam,
                                              int* __restrict__ gcur,
                                              int2* __restrict__ seg, int E, int nb)
{
    __shared__ int hist[1024];
    __shared__ int base_[1024];
    __shared__ int lcur[1024];
    int t = threadIdx.x;
    for (int i = t; i < 1024; i += PTH) { hist[i] = 0; base_[i] = 0; lcur[i] = 0; }
    __syncthreads();
    int b0 = blockIdx.x * PCH;
#pragma unroll 4
    for (int k = 0; k < PCH / PTH; ++k) {
        int i = b0 + k * PTH + t;
        if (i < E) {
            unsigned b = ((unsigned)dst[i]) >> SHIFT;
            if (b < 1024u) atomicAdd(&hist[b], 1);
        }
    }
    __syncthreads();
    for (int i = t; i < nb; i += PTH) {
        int c = hist[i];
        if (c) base_[i] = atomicAdd(&gcur[i], c);
    }
    __syncthreads();
#pragma unroll 4
    for (int k = 0; k < PCH / PTH; ++k) {
        int i = b0 + k * PTH + t;
        if (i < E) {
            int d = dst[i];
            unsigned b = ((unsigned)d) >> SHIFT;
            if (b < 1024u) {
                int s = src[i];
                float wv = w[i];
                float g  = gam[s];
                unsigned short wb  = f2bf(wv);
                unsigned short wdb = f2bf(fabsf(wv) * (g - 1.0f));
                int pos = base_[b] + atomicAdd(&lcur[b], 1);
                if (pos >= 0 && pos < E) {
                    int2 r;
                    r.x = ((d & (SPAN - 1)) << 24) | (s & 0xFFFFFF);
                    r.y = ((unsigned)wb << 16) | wdb;
                    seg[pos] = r;
                }
            }
        }
    }
}

// ---------- per-bucket LDS counting sort -> exact per-node order + starts ----------
__global__ __launch_bounds__(256) void k_sortb(
    const int2* __restrict__ seg, const int* __restrict__ gstart,
    int* __restrict__ starts, int2* __restrict__ seg2, int n, int E)
{
    __shared__ int hist[SPAN];
    __shared__ int sb[SPAN];
    __shared__ int cur[SPAN];
    int b = blockIdx.x;
    int t = threadIdx.x;
    if (b == 0 && t == 0) starts[n] = E;
    int segL = gstart[b], segR = gstart[b + 1];
    if (segL < 0) segL = 0;
    if (segR > E) segR = E;
    if (t < SPAN) hist[t] = 0;
    __syncthreads();
    {
        int j = segL + t;
        for (; j + 768 < segR; j += 1024) {
            unsigned d0 = ((unsigned)seg[j      ].x) >> 24;
            unsigned d1 = ((unsigned)seg[j + 256].x) >> 24;
            unsigned d2 = ((unsigned)seg[j + 512].x) >> 24;
            unsigned d3 = ((unsigned)seg[j + 768].x) >> 24;
            atomicAdd(&hist[d0], 1);
            atomicAdd(&hist[d1], 1);
            atomicAdd(&hist[d2], 1);
            atomicAdd(&hist[d3], 1);
        }
        for (; j < segR; j += 256) {
            unsigned dl = ((unsigned)seg[j].x) >> 24;
            atomicAdd(&hist[dl], 1);
        }
    }
    __syncthreads();
    if (t < SPAN) sb[t] = hist[t];
    __syncthreads();
    for (int off = 1; off < SPAN; off <<= 1) {
        int a = 0;
        if (t < SPAN) { a = sb[t]; if (t >= off) a += sb[t - off]; }
        __syncthreads();
        if (t < SPAN) sb[t] = a;
        __syncthreads();
    }
    if (t < SPAN) {
        int ls = sb[t] - hist[t];
        cur[t] = segL + ls;
        int node = b * SPAN + t;
        if (node < n) starts[node] = segL + ls;
    }
    __syncthreads();
    {
        int j = segL + t;
        for (; j + 768 < segR; j += 1024) {
            int2 r0 = seg[j      ];
            int2 r1 = seg[j + 256];
            int2 r2 = seg[j + 512];
            int2 r3 = seg[j + 768];
            int p0 = atomicAdd(&cur[((unsigned)r0.x) >> 24], 1);
            int p1 = atomicAdd(&cur[((unsigned)r1.x) >> 24], 1);
            int p2 = atomicAdd(&cur[((unsigned)r2.x) >> 24], 1);
            int p3 = atomicAdd(&cur[((unsigned)r3.x) >> 24], 1);
            if (p0 >= 0 && p0 < E) seg2[p0] = make_int2(r0.x & 0xFFFFFF, r0.y);
            if (p1 >= 0 && p1 < E) seg2[p1] = make_int2(r1.x & 0xFFFFFF, r1.y);
            if (p2 >= 0 && p2 < E) seg2[p2] = make_int2(r2.x & 0xFFFFFF, r2.y);
            if (p3 >= 0 && p3 < E) seg2[p3] = make_int2(r3.x & 0xFFFFFF, r3.y);
        }
        for (; j < segR; j += 256) {
            int2 r = seg[j];
            int pos = atomicAdd(&cur[((unsigned)r.x) >> 24], 1);
            if (pos >= 0 && pos < E) seg2[pos] = make_int2(r.x & 0xFFFFFF, r.y);
        }
    }
}

// ---------- precompute ybf[s] = bf16(gam[s] * x[s]) into dead seg buffer ----------
__global__ __launch_bounds__(256) void k_prep(const float* __restrict__ x,
                                              const float* __restrict__ gam,
                                              ushort4* __restrict__ ybf, int n)
{
    long long t = (long long)blockIdx.x * blockDim.x + threadIdx.x;
    int node = (int)(t / DQ);
    if (node >= n) return;
    int part = (int)(t % DQ);
    float g = gam[node];
    float4 v = reinterpret_cast<const float4*>(x)[(size_t)node * DQ + part];
    ushort4 o;
    o.x = f2bf(v.x * g);
    o.y = f2bf(v.y * g);
    o.z = f2bf(v.z * g);
    o.w = f2bf(v.w * g);
    ybf[(size_t)node * DQ + part] = o;
}

// ---------- gather: 12 lanes/node, single random stream, 4-wide pipeline ----------
__global__ __launch_bounds__(256) void k_gather(
    const ushort4* __restrict__ ybf,
    const int* __restrict__ starts,
    const int2* __restrict__ srec,
    float* __restrict__ num, float* __restrict__ den, int n, int E)
{
    long long t = (long long)blockIdx.x * blockDim.x + threadIdx.x;
    int node = (int)(t / DQ);
    if (node >= n) return;
    int part = (int)(t % DQ);
    int j0 = starts[node], j1 = starts[node + 1];
    if (j0 < 0) j0 = 0;
    if (j1 > E) j1 = E;
    float4 acc = make_float4(0.f, 0.f, 0.f, 0.f);
    float dacc = 0.f;
    int j = j0;
    for (; j + 3 < j1; j += 4) {
        int2 r0 = srec[j];
        int2 r1 = srec[j + 1];
        int2 r2 = srec[j + 2];
        int2 r3 = srec[j + 3];
        ushort4 a0 = ybf[(size_t)(r0.x) * DQ + part];
        ushort4 a1 = ybf[(size_t)(r1.x) * DQ + part];
        ushort4 a2 = ybf[(size_t)(r2.x) * DQ + part];
        ushort4 a3 = ybf[(size_t)(r3.x) * DQ + part];
        float w0 = bf2f((unsigned short)(((unsigned)r0.y) >> 16));
        float w1 = bf2f((unsigned short)(((unsigned)r1.y) >> 16));
        float w2 = bf2f((unsigned short)(((unsigned)r2.y) >> 16));
        float w3 = bf2f((unsigned short)(((unsigned)r3.y) >> 16));
        acc.x = fmaf(w0, bf2f(a0.x), acc.x);
        acc.y = fmaf(w0, bf2f(a0.y), acc.y);
        acc.z = fmaf(w0, bf2f(a0.z), acc.z);
        acc.w = fmaf(w0, bf2f(a0.w), acc.w);
        acc.x = fmaf(w1, bf2f(a1.x), acc.x);
        acc.y = fmaf(w1, bf2f(a1.y), acc.y);
        acc.z = fmaf(w1, bf2f(a1.z), acc.z);
        acc.w = fmaf(w1, bf2f(a1.w), acc.w);
        acc.x = fmaf(w2, bf2f(a2.x), acc.x);
        acc.y = fmaf(w2, bf2f(a2.y), acc.y);
        acc.z = fmaf(w2, bf2f(a2.z), acc.z);
        acc.w = fmaf(w2, bf2f(a2.w), acc.w);
        acc.x = fmaf(w3, bf2f(a3.x), acc.x);
        acc.y = fmaf(w3, bf2f(a3.y), acc.y);
        acc.z = fmaf(w3, bf2f(a3.z), acc.z);
        acc.w = fmaf(w3, bf2f(a3.w), acc.w);
        dacc += bf2f((unsigned short)(((unsigned)r0.y) & 0xFFFF))
              + bf2f((unsigned short)(((unsigned)r1.y) & 0xFFFF))
              + bf2f((unsigned short)(((unsigned)r2.y) & 0xFFFF))
              + bf2f((unsigned short)(((unsigned)r3.y) & 0xFFFF));
    }
    for (; j < j1; ++j) {
        int2 r0 = srec[j];
        ushort4 a0 = ybf[(size_t)(r0.x) * DQ + part];
        float w0 = bf2f((unsigned short)(((unsigned)r0.y) >> 16));
        acc.x = fmaf(w0, bf2f(a0.x), acc.x);
        acc.y = fmaf(w0, bf2f(a0.y), acc.y);
        acc.z = fmaf(w0, bf2f(a0.z), acc.z);
        acc.w = fmaf(w0, bf2f(a0.w), acc.w);
        dacc += bf2f((unsigned short)(((unsigned)r0.y) & 0xFFFF));
    }
    reinterpret_cast<float4*>(num)[(size_t)node * DQ + part] = acc;
    if (part == 0) den[node] = dacc;
}

// ---------- fallback: atomic edge scatter ----------
__global__ void k_init_atomic(float* __restrict__ den, float* __restrict__ num, int n)
{
    int i = blockIdx.x * blockDim.x + threadIdx.x;
    if (i >= n) return;
    den[i] = 0.0f;
    float4* nr = reinterpret_cast<float4*>(num) + (size_t)i * DQ;
    float4 z = make_float4(0.f, 0.f, 0.f, 0.f);
#pragma unroll
    for (int q = 0; q < DQ; ++q) nr[q] = z;
}

__global__ void k_edge_atomic(const float* __restrict__ x, const float* __restrict__ gam,
                              const int* __restrict__ src, const int* __restrict__ dst,
                              const float* __restrict__ w,
                              float* __restrict__ num, float* __restrict__ den, int E)
{
    long long t = (long long)blockIdx.x * blockDim.x + threadIdx.x;
    int e = (int)(t / DQ);
    if (e >= E) return;
    int part = (int)(t % DQ);
    int s = src[e];
    int d = dst[e];
    float we = w[e];
    float g  = gam[s];
    float4 xv = reinterpret_cast<const float4*>(x)[(size_t)s * DQ + part];
    float c = we * g;
    float* np_ = num + (size_t)d * D + part * 4;
    atomicAdd(np_ + 0, c * xv.x);
    atomicAdd(np_ + 1, c * xv.y);
    atomicAdd(np_ + 2, c * xv.z);
    atomicAdd(np_ + 3, c * xv.w);
    if (part == 0) atomicAdd(den + d, fabsf(we) * (g - 1.0f));
}

// mobius_scalar_mul(0.5, v) followed by _project, in place.
__device__ __forceinline__ void half_mul_project(float* v)
{
    float s = 0.f;
#pragma unroll
    for (int k = 0; k < D; ++k) s += v[k] * v[k];
    float nrm = sqrtf(s);
    float ncl = fmaxf(nrm, F_EPS);
    float t   = tanhf(0.5f * artanh_c(ncl));
    float sc  = t / ncl;
    float rn  = nrm * sc;
    if (rn > MAXNORM) sc *= MAXNORM / fmaxf(rn, F_EPS);
#pragma unroll
    for (int k = 0; k < D; ++k) v[k] *= sc;
}

// k_node v4: closed-form (no mx[] array, no spill — R12) + LDS-staged W
// (broadcast ds_read, removes the per-FMA global-load stall that kept R12 at
// 90us) + 4 independent accumulator chains per j-group (breaks the serial
// fmaf dependency chain). Outer loops rolled: ~250-instr bodies, no I$
// thrash (R10/R11 lesson).
__global__ __launch_bounds__(256) void k_node(
    float* __restrict__ out,
    const float* __restrict__ den,
    const float* __restrict__ h_init,
    const float* __restrict__ Wm,
    const float* __restrict__ bias, int n)
{
    __shared__ float Ws[D * D];
    __shared__ float bs[D];
    for (int k = threadIdx.x; k < D * D; k += 256) Ws[k] = Wm[k];
    if (threadIdx.x < D) bs[threadIdx.x] = bias[threadIdx.x];
    __syncthreads();

    int i = blockIdx.x * blockDim.x + threadIdx.x;
    if (i >= n) return;

    float a[D];
    {
        const float4* nr = reinterpret_cast<const float4*>(out) + (size_t)i * DQ;
        float dinv = 1.0f / clampabs(den[i]);
#pragma unroll
        for (int q = 0; q < DQ; ++q) {
            float4 v = nr[q];
            a[q * 4 + 0] = v.x * dinv;
            a[q * 4 + 1] = v.y * dinv;
            a[q * 4 + 2] = v.z * dinv;
            a[q * 4 + 3] = v.w * dinv;
        }
    }
    half_mul_project(a);

    {
        float b[D];
        const float4* hr = reinterpret_cast<const float4*>(h_init) + (size_t)i * DQ;
#pragma unroll
        for (int q = 0; q < DQ; ++q) {
            float4 v = hr[q];
            b[q * 4 + 0] = v.x; b[q * 4 + 1] = v.y;
            b[q * 4 + 2] = v.z; b[q * 4 + 3] = v.w;
        }
        float sa = 0.f, sb = 0.f;
#pragma unroll
        for (int k = 0; k < D; ++k) { sa += a[k] * a[k]; sb += b[k] * b[k]; }
        float ga = 2.0f / fmaxf(1.0f - sa, F_EPS);
        float gb = 2.0f / fmaxf(1.0f - sb, F_EPS);
        const float wa = 0.9f, wb = 0.1f;
        float dinv = 1.0f / clampabs(wa * (ga - 1.0f) + wb * (gb - 1.0f));
        float ca = wa * ga * dinv, cb = wb * gb * dinv;
#pragma unroll
        for (int k = 0; k < D; ++k) a[k] = ca * a[k] + cb * b[k];
        half_mul_project(a);
    }

    // ---- fused mobius_matvec + mobius_add(expmap0(bias)) + project
    float sa2 = 0.f;
#pragma unroll
    for (int k = 0; k < D; ++k) sa2 += a[k] * a[k];
    float xn = fmaxf(sqrtf(sa2), F_EPS);

    // pass 1: smx = ||W a||^2, xyr = <W a, bias>; 4 chains per group
    float smx = 0.f, xyr = 0.f;
    for (int j4 = 0; j4 < D; j4 += 4) {
        const float* w0 = &Ws[(j4 + 0) * D];
        const float* w1 = &Ws[(j4 + 1) * D];
        const float* w2 = &Ws[(j4 + 2) * D];
        const float* w3 = &Ws[(j4 + 3) * D];
        float acc0 = 0.f, acc1 = 0.f, acc2 = 0.f, acc3 = 0.f;
#pragma unroll
        for (int k = 0; k < D; ++k) {
            float ak = a[k];
            acc0 = fmaf(w0[k], ak, acc0);
            acc1 = fmaf(w1[k], ak, acc1);
            acc2 = fmaf(w2[k], ak, acc2);
            acc3 = fmaf(w3[k], ak, acc3);
        }
        smx += acc0 * acc0 + acc1 * acc1 + acc2 * acc2 + acc3 * acc3;
        xyr += acc0 * bs[j4 + 0] + acc1 * bs[j4 + 1]
             + acc2 * bs[j4 + 2] + acc3 * bs[j4 + 3];
    }
    float mxnr = sqrtf(smx);
    float mxn = fmaxf(mxnr, F_EPS);
    float tt = tanhf((mxn / xn) * artanh_c(xn));
    float sc = tt / mxn;
    float rn = mxnr * sc;
    if (rn > MAXNORM) sc *= MAXNORM / fmaxf(rn, F_EPS);

    float bn2 = 0.f;
#pragma unroll
    for (int k = 0; k < D; ++k) bn2 = fmaf(bs[k], bs[k], bn2);
    float bn  = fmaxf(sqrtf(bn2), F_EPS);
    float ebs = tanhf(bn) / bn;
    float y2  = ebs * ebs * bn2;

    float x2 = sc * sc * smx;
    float xy = sc * ebs * xyr;
    float c1 = 1.0f + 2.0f * xy + y2;
    float c2 = 1.0f - x2;
    float dn3 = 1.0f / fmaxf(1.0f + 2.0f * xy + x2 * y2, F_EPS);

    float s3 = dn3 * dn3 * (c1 * c1 * sc * sc * smx
                            + 2.0f * c1 * c2 * sc * ebs * xyr
                            + c2 * c2 * ebs * ebs * bn2);
    float nrm3 = sqrtf(s3);
    float fp = (nrm3 > MAXNORM) ? (MAXNORM / fmaxf(nrm3, F_EPS)) : 1.0f;

    float CA = c1 * sc * dn3 * fp;
    float CB = c2 * ebs * dn3 * fp;

    // pass 2: recompute dots, 4 chains, store float4
    float4* orow = reinterpret_cast<float4*>(out) + (size_t)i * DQ;
    for (int q = 0; q < DQ; ++q) {
        const float* w0 = &Ws[(q * 4 + 0) * D];
        const float* w1 = &Ws[(q * 4 + 1) * D];
        const float* w2 = &Ws[(q * 4 + 2) * D];
        const float* w3 = &Ws[(q * 4 + 3) * D];
        float acc0 = 0.f, acc1 = 0.f, acc2 = 0.f, acc3 = 0.f;
#pragma unroll
        for (int k = 0; k < D; ++k) {
            float ak = a[k];
            acc0 = fmaf(w0[k], ak, acc0);
            acc1 = fmaf(w1[k], ak, acc1);
            acc2 = fmaf(w2[k], ak, acc2);
            acc3 = fmaf(w3[k], ak, acc3);
        }
        float4 v;
        v.x = fmaf(CA, acc0, CB * bs[q * 4 + 0]);
        v.y = fmaf(CA, acc1, CB * bs[q * 4 + 1]);
        v.z = fmaf(CA, acc2, CB * bs[q * 4 + 2]);
        v.w = fmaf(CA, acc3, CB * bs[q * 4 + 3]);
        orow[q] = v;
    }
}

extern "C" void kernel_launch(void* const* d_in, const int* in_sizes, int n_in,
                              void* d_out, int out_size, void* d_ws, size_t ws_size,
                              hipStream_t stream)
{
    const float* x      = (const float*)d_in[0];
    const float* h_init = (const float*)d_in[1];
    const float* edge_w = (const float*)d_in[2];
    const float* W      = (const float*)d_in[3];
    const float* bias   = (const float*)d_in[4];
    const int*   esrc   = (const int*)d_in[5];
    const int*   edst   = (const int*)d_in[6];
    float* out = (float*)d_out;

    int n = in_sizes[0] / D;
    int E = in_sizes[2];
    int nb = (n + SPAN - 1) >> SHIFT;

    // ws layout
    char* p = (char*)d_ws;
    float* gam    = (float*)p;             p += (size_t)n * 4;
    float* den    = (float*)p;             p += (size_t)n * 4;
    int*   ghist  = (int*)p;               p += (size_t)nb * 4;
    int*   gstart = (int*)p;               p += (size_t)(nb + 1) * 4;
    int*   gcur   = (int*)p;               p += (size_t)nb * 4;
    int*   starts = (int*)p;               p += (size_t)(n + 1) * 4;
    p = (char*)(((uintptr_t)p + 15) & ~(uintptr_t)15);   // align 16
    int2*  seg    = (int2*)p;              p += (size_t)E * 8;
    int2*  seg2   = (int2*)p;              p += (size_t)E * 8;
    size_t need1 = (size_t)(p - (char*)d_ws);
    ushort4* ybf = (ushort4*)seg;
    bool ybf_fits = ((size_t)E * 8 >= (size_t)n * D * 2);

    k_gamma<<<(n + 255) / 256, 256, 0, stream>>>(x, gam, ghist, n, nb);

    bool shape_ok = (nb <= 1024) && (n < (1 << 24));
    if (shape_ok && ybf_fits && need1 <= ws_size) {
        int pb = (E + PCH - 1) / PCH;
        k_hist<<<pb, PTH, 0, stream>>>(edst, ghist, E, nb);
        k_scanb<<<1, 1024, 0, stream>>>(ghist, gstart, gcur, nb, E);
        k_part<<<pb, PTH, 0, stream>>>(esrc, edst, edge_w, gam, gcur, seg, E, nb);
        k_sortb<<<nb, 256, 0, stream>>>(seg, gstart, starts, seg2, n, E);
        long long tot = (long long)n * DQ;
        int gg = (int)((tot + 255) / 256);
        k_prep<<<gg, 256, 0, stream>>>(x, gam, ybf, n);
        k_gather<<<gg, 256, 0, stream>>>(ybf, starts, seg2, out, den, n, E);
    } else {
        k_init_atomic<<<(n + 255) / 256, 256, 0, stream>>>(den, out, n);
        long long tot = (long long)E * DQ;
        k_edge_atomic<<<(int)((tot + 255) / 256), 256, 0, stream>>>(x, gam, esrc, edst, edge_w, out, den, E);
    }

    k_node<<<(n + 255) / 256, 256, 0, stream>>>(out, den, h_init, W, bias, n);
}

// Round 14
// 156.676 us; speedup vs baseline: 1.0489x; 1.0131x over previous
//
#include <hip/hip_runtime.h>
#include <math.h>

#define D  48
#define DQ 12        // D/4
#define SPAN 128     // nodes per bucket
#define SHIFT 7      // log2(SPAN)
#define PCH  8192    // edges per hist/partition block
#define PTH  512     // threads for hist/part
#define NPB  16      // nodes per k_node block (16 threads/node)
#define WSTR 52      // Ws row stride (16B-aligned, low bank conflict)

constexpr float F_EPS   = 1e-15f;
constexpr float MAXNORM = 1.0f - 1e-5f;

__device__ __forceinline__ float artanh_c(float x) {
    x = fminf(x, 1.0f - 1e-7f);
    x = fmaxf(x, -1.0f + 1e-7f);
    return atanhf(x);
}

__device__ __forceinline__ float clampabs(float x) {
    return (x >= 0.0f) ? fmaxf(x, 1e-10f) : fminf(x, -1e-10f);
}

__device__ __forceinline__ unsigned short f2bf(float f) {
    unsigned u = __float_as_uint(f);
    u += 0x7FFFu + ((u >> 16) & 1u);
    return (unsigned short)(u >> 16);
}

__device__ __forceinline__ float bf2f(unsigned short u) {
    return __uint_as_float(((unsigned)u) << 16);
}

// ---------- per-node gamma + zero bucket histogram ----------
__global__ void k_gamma(const float* __restrict__ x, float* __restrict__ gam,
                        int* __restrict__ ghist, int n, int nb)
{
    int i = blockIdx.x * blockDim.x + threadIdx.x;
    if (i < nb) ghist[i] = 0;
    if (i >= n) return;
    const float4* xr = reinterpret_cast<const float4*>(x) + (size_t)i * DQ;
    float s = 0.0f;
#pragma unroll
    for (int q = 0; q < DQ; ++q) {
        float4 v = xr[q];
        s += v.x * v.x + v.y * v.y + v.z * v.z + v.w * v.w;
    }
    gam[i] = 2.0f / fmaxf(1.0f - s, F_EPS);
}

// ---------- bucket histogram (LDS-staged, unrolled) ----------
__global__ __launch_bounds__(PTH) void k_hist(const int* __restrict__ dst,
                                              int* __restrict__ ghist, int E, int nb)
{
    __shared__ int h[1024];
    int t = threadIdx.x;
    for (int i = t; i < 1024; i += PTH) h[i] = 0;
    __syncthreads();
    int base = blockIdx.x * PCH;
#pragma unroll 4
    for (int k = 0; k < PCH / PTH; ++k) {
        int i = base + k * PTH + t;
        if (i < E) {
            unsigned b = ((unsigned)dst[i]) >> SHIFT;
            if (b < 1024u) atomicAdd(&h[b], 1);
        }
    }
    __syncthreads();
    for (int i = t; i < nb; i += PTH) {
        int c = h[i];
        if (c) atomicAdd(&ghist[i], c);
    }
}

// ---------- exclusive scan of bucket counts (single block, nb <= 1024) ----------
__global__ __launch_bounds__(1024) void k_scanb(const int* __restrict__ ghist,
                                                int* __restrict__ gstart,
                                                int* __restrict__ gcur, int nb, int E)
{
    __shared__ int sh[1024];
    int t = threadIdx.x;
    int v = (t < nb) ? ghist[t] : 0;
    sh[t] = v;
    __syncthreads();
    for (int off = 1; off < 1024; off <<= 1) {
        int a = sh[t];
        int b = (t >= off) ? sh[t - off] : 0;
        __syncthreads();
        sh[t] = a + b;
        __syncthreads();
    }
    if (t < nb) { int s = sh[t] - v; gstart[t] = s; gcur[t] = s; }
    if (t == 0) gstart[nb] = E;
}

// ---------- partition: bucket-burst records with packed bf16 weights ----------
__global__ __launch_bounds__(PTH) void k_part(const int* __restrict__ src,
                                              const int* __restrict__ dst,
                                              const float* __restrict__ w,
                                              const float* __restrict__ gam,
                                              int* __restrict__ gcur,
                                              int2* __restrict__ seg, int E, int nb)
{
    __shared__ int hist[1024];
    __shared__ int base_[1024];
    __shared__ int lcur[1024];
    int t = threadIdx.x;
    for (int i = t; i < 1024; i += PTH) { hist[i] = 0; base_[i] = 0; lcur[i] = 0; }
    __syncthreads();
    int b0 = blockIdx.x * PCH;
#pragma unroll 4
    for (int k = 0; k < PCH / PTH; ++k) {
        int i = b0 + k * PTH + t;
        if (i < E) {
            unsigned b = ((unsigned)dst[i]) >> SHIFT;
            if (b < 1024u) atomicAdd(&hist[b], 1);
        }
    }
    __syncthreads();
    for (int i = t; i < nb; i += PTH) {
        int c = hist[i];
        if (c) base_[i] = atomicAdd(&gcur[i], c);
    }
    __syncthreads();
#pragma unroll 4
    for (int k = 0; k < PCH / PTH; ++k) {
        int i = b0 + k * PTH + t;
        if (i < E) {
            int d = dst[i];
            unsigned b = ((unsigned)d) >> SHIFT;
            if (b < 1024u) {
                int s = src[i];
                float wv = w[i];
                float g  = gam[s];
                unsigned short wb  = f2bf(wv);
                unsigned short wdb = f2bf(fabsf(wv) * (g - 1.0f));
                int pos = base_[b] + atomicAdd(&lcur[b], 1);
                if (pos >= 0 && pos < E) {
                    int2 r;
                    r.x = ((d & (SPAN - 1)) << 24) | (s & 0xFFFFFF);
                    r.y = ((unsigned)wb << 16) | wdb;
                    seg[pos] = r;
                }
            }
        }
    }
}

// ---------- per-bucket LDS counting sort -> exact per-node order + starts ----------
__global__ __launch_bounds__(256) void k_sortb(
    const int2* __restrict__ seg, const int* __restrict__ gstart,
    int* __restrict__ starts, int2* __restrict__ seg2, int n, int E)
{
    __shared__ int hist[SPAN];
    __shared__ int sb[SPAN];
    __shared__ int cur[SPAN];
    int b = blockIdx.x;
    int t = threadIdx.x;
    if (b == 0 && t == 0) starts[n] = E;
    int segL = gstart[b], segR = gstart[b + 1];
    if (segL < 0) segL = 0;
    if (segR > E) segR = E;
    if (t < SPAN) hist[t] = 0;
    __syncthreads();
    {
        int j = segL + t;
        for (; j + 768 < segR; j += 1024) {
            unsigned d0 = ((unsigned)seg[j      ].x) >> 24;
            unsigned d1 = ((unsigned)seg[j + 256].x) >> 24;
            unsigned d2 = ((unsigned)seg[j + 512].x) >> 24;
            unsigned d3 = ((unsigned)seg[j + 768].x) >> 24;
            atomicAdd(&hist[d0], 1);
            atomicAdd(&hist[d1], 1);
            atomicAdd(&hist[d2], 1);
            atomicAdd(&hist[d3], 1);
        }
        for (; j < segR; j += 256) {
            unsigned dl = ((unsigned)seg[j].x) >> 24;
            atomicAdd(&hist[dl], 1);
        }
    }
    __syncthreads();
    if (t < SPAN) sb[t] = hist[t];
    __syncthreads();
    for (int off = 1; off < SPAN; off <<= 1) {
        int a = 0;
        if (t < SPAN) { a = sb[t]; if (t >= off) a += sb[t - off]; }
        __syncthreads();
        if (t < SPAN) sb[t] = a;
        __syncthreads();
    }
    if (t < SPAN) {
        int ls = sb[t] - hist[t];
        cur[t] = segL + ls;
        int node = b * SPAN + t;
        if (node < n) starts[node] = segL + ls;
    }
    __syncthreads();
    {
        int j = segL + t;
        for (; j + 768 < segR; j += 1024) {
            int2 r0 = seg[j      ];
            int2 r1 = seg[j + 256];
            int2 r2 = seg[j + 512];
            int2 r3 = seg[j + 768];
            int p0 = atomicAdd(&cur[((unsigned)r0.x) >> 24], 1);
            int p1 = atomicAdd(&cur[((unsigned)r1.x) >> 24], 1);
            int p2 = atomicAdd(&cur[((unsigned)r2.x) >> 24], 1);
            int p3 = atomicAdd(&cur[((unsigned)r3.x) >> 24], 1);
            if (p0 >= 0 && p0 < E) seg2[p0] = make_int2(r0.x & 0xFFFFFF, r0.y);
            if (p1 >= 0 && p1 < E) seg2[p1] = make_int2(r1.x & 0xFFFFFF, r1.y);
            if (p2 >= 0 && p2 < E) seg2[p2] = make_int2(r2.x & 0xFFFFFF, r2.y);
            if (p3 >= 0 && p3 < E) seg2[p3] = make_int2(r3.x & 0xFFFFFF, r3.y);
        }
        for (; j < segR; j += 256) {
            int2 r = seg[j];
            int pos = atomicAdd(&cur[((unsigned)r.x) >> 24], 1);
            if (pos >= 0 && pos < E) seg2[pos] = make_int2(r.x & 0xFFFFFF, r.y);
        }
    }
}

// ---------- precompute ybf[s] = bf16(gam[s] * x[s]) into dead seg buffer ----------
__global__ __launch_bounds__(256) void k_prep(const float* __restrict__ x,
                                              const float* __restrict__ gam,
                                              ushort4* __restrict__ ybf, int n)
{
    long long t = (long long)blockIdx.x * blockDim.x + threadIdx.x;
    int node = (int)(t / DQ);
    if (node >= n) return;
    int part = (int)(t % DQ);
    float g = gam[node];
    float4 v = reinterpret_cast<const float4*>(x)[(size_t)node * DQ + part];
    ushort4 o;
    o.x = f2bf(v.x * g);
    o.y = f2bf(v.y * g);
    o.z = f2bf(v.z * g);
    o.w = f2bf(v.w * g);
    ybf[(size_t)node * DQ + part] = o;
}

// ---------- gather: 12 lanes/node, single random stream, 4-wide pipeline ----------
__global__ __launch_bounds__(256) void k_gather(
    const ushort4* __restrict__ ybf,
    const int* __restrict__ starts,
    const int2* __restrict__ srec,
    float* __restrict__ num, float* __restrict__ den, int n, int E)
{
    long long t = (long long)blockIdx.x * blockDim.x + threadIdx.x;
    int node = (int)(t / DQ);
    if (node >= n) return;
    int part = (int)(t % DQ);
    int j0 = starts[node], j1 = starts[node + 1];
    if (j0 < 0) j0 = 0;
    if (j1 > E) j1 = E;
    float4 acc = make_float4(0.f, 0.f, 0.f, 0.f);
    float dacc = 0.f;
    int j = j0;
    for (; j + 3 < j1; j += 4) {
        int2 r0 = srec[j];
        int2 r1 = srec[j + 1];
        int2 r2 = srec[j + 2];
        int2 r3 = srec[j + 3];
        ushort4 a0 = ybf[(size_t)(r0.x) * DQ + part];
        ushort4 a1 = ybf[(size_t)(r1.x) * DQ + part];
        ushort4 a2 = ybf[(size_t)(r2.x) * DQ + part];
        ushort4 a3 = ybf[(size_t)(r3.x) * DQ + part];
        float w0 = bf2f((unsigned short)(((unsigned)r0.y) >> 16));
        float w1 = bf2f((unsigned short)(((unsigned)r1.y) >> 16));
        float w2 = bf2f((unsigned short)(((unsigned)r2.y) >> 16));
        float w3 = bf2f((unsigned short)(((unsigned)r3.y) >> 16));
        acc.x = fmaf(w0, bf2f(a0.x), acc.x);
        acc.y = fmaf(w0, bf2f(a0.y), acc.y);
        acc.z = fmaf(w0, bf2f(a0.z), acc.z);
        acc.w = fmaf(w0, bf2f(a0.w), acc.w);
        acc.x = fmaf(w1, bf2f(a1.x), acc.x);
        acc.y = fmaf(w1, bf2f(a1.y), acc.y);
        acc.z = fmaf(w1, bf2f(a1.z), acc.z);
        acc.w = fmaf(w1, bf2f(a1.w), acc.w);
        acc.x = fmaf(w2, bf2f(a2.x), acc.x);
        acc.y = fmaf(w2, bf2f(a2.y), acc.y);
        acc.z = fmaf(w2, bf2f(a2.z), acc.z);
        acc.w = fmaf(w2, bf2f(a2.w), acc.w);
        acc.x = fmaf(w3, bf2f(a3.x), acc.x);
        acc.y = fmaf(w3, bf2f(a3.y), acc.y);
        acc.z = fmaf(w3, bf2f(a3.z), acc.z);
        acc.w = fmaf(w3, bf2f(a3.w), acc.w);
        dacc += bf2f((unsigned short)(((unsigned)r0.y) & 0xFFFF))
              + bf2f((unsigned short)(((unsigned)r1.y) & 0xFFFF))
              + bf2f((unsigned short)(((unsigned)r2.y) & 0xFFFF))
              + bf2f((unsigned short)(((unsigned)r3.y) & 0xFFFF));
    }
    for (; j < j1; ++j) {
        int2 r0 = srec[j];
        ushort4 a0 = ybf[(size_t)(r0.x) * DQ + part];
        float w0 = bf2f((unsigned short)(((unsigned)r0.y) >> 16));
        acc.x = fmaf(w0, bf2f(a0.x), acc.x);
        acc.y = fmaf(w0, bf2f(a0.y), acc.y);
        acc.z = fmaf(w0, bf2f(a0.z), acc.z);
        acc.w = fmaf(w0, bf2f(a0.w), acc.w);
        dacc += bf2f((unsigned short)(((unsigned)r0.y) & 0xFFFF));
    }
    reinterpret_cast<float4*>(num)[(size_t)node * DQ + part] = acc;
    if (part == 0) den[node] = dacc;
}

// ---------- fallback: atomic edge scatter ----------
__global__ void k_init_atomic(float* __restrict__ den, float* __restrict__ num, int n)
{
    int i = blockIdx.x * blockDim.x + threadIdx.x;
    if (i >= n) return;
    den[i] = 0.0f;
    float4* nr = reinterpret_cast<float4*>(num) + (size_t)i * DQ;
    float4 z = make_float4(0.f, 0.f, 0.f, 0.f);
#pragma unroll
    for (int q = 0; q < DQ; ++q) nr[q] = z;
}

__global__ void k_edge_atomic(const float* __restrict__ x, const float* __restrict__ gam,
                              const int* __restrict__ src, const int* __restrict__ dst,
                              const float* __restrict__ w,
                              float* __restrict__ num, float* __restrict__ den, int E)
{
    long long t = (long long)blockIdx.x * blockDim.x + threadIdx.x;
    int e = (int)(t / DQ);
    if (e >= E) return;
    int part = (int)(t % DQ);
    int s = src[e];
    int d = dst[e];
    float we = w[e];
    float g  = gam[s];
    float4 xv = reinterpret_cast<const float4*>(x)[(size_t)s * DQ + part];
    float c = we * g;
    float* np_ = num + (size_t)d * D + part * 4;
    atomicAdd(np_ + 0, c * xv.x);
    atomicAdd(np_ + 1, c * xv.y);
    atomicAdd(np_ + 2, c * xv.z);
    atomicAdd(np_ + 3, c * xv.w);
    if (part == 0) atomicAdd(den + d, fabsf(we) * (g - 1.0f));
}

// k_node v5: 16 threads per node (16x the wave count of thread-per-node —
// R13 was grid-starved at 1.5 waves/SIMD, OccupancyPercent 15%). Each lane
// owns elems/rows {l, l+16, l+32}; norms/dots via __shfl_xor(.,16) group
// reductions; a staged per-node in LDS (broadcast reads for the row dots);
// per-lane row accs stay in registers -> no pass-2 dot recompute.
__global__ __launch_bounds__(256) void k_node(
    float* __restrict__ out,
    const float* __restrict__ den,
    const float* __restrict__ h_init,
    const float* __restrict__ Wm,
    const float* __restrict__ bias, int n)
{
    __shared__ float Ws[D * WSTR];
    __shared__ float bs[D];
    __shared__ float aLds[NPB][D];
    int t = threadIdx.x;
    for (int k = t; k < D * D; k += 256) Ws[(k / D) * WSTR + (k % D)] = Wm[k];
    if (t < D) bs[t] = bias[t];
    __syncthreads();

    int grp = t >> 4;
    int lane = t & 15;
    int i = blockIdx.x * NPB + grp;
    bool act = (i < n);

    // group sum over 16 lanes
    auto gsum = [](float v) {
        v += __shfl_xor(v, 1, 16);
        v += __shfl_xor(v, 2, 16);
        v += __shfl_xor(v, 4, 16);
        v += __shfl_xor(v, 8, 16);
        return v;
    };

    // ---- 1) a = num/clamp_abs(den); mobius_scalar_mul(0.5)+project
    float a0 = 0.f, a1 = 0.f, a2 = 0.f;
    if (act) {
        float dinv = 1.0f / clampabs(den[i]);
        const float* nr = out + (size_t)i * D;
        a0 = nr[lane] * dinv;
        a1 = nr[lane + 16] * dinv;
        a2 = nr[lane + 32] * dinv;
    }
    {
        float s = gsum(a0 * a0 + a1 * a1 + a2 * a2);
        float nrm = sqrtf(s);
        float ncl = fmaxf(nrm, F_EPS);
        float tt = tanhf(0.5f * artanh_c(ncl));
        float sc = tt / ncl;
        float rn = nrm * sc;
        if (rn > MAXNORM) sc *= MAXNORM / fmaxf(rn, F_EPS);
        a0 *= sc; a1 *= sc; a2 *= sc;
    }

    // ---- 2) pair midpoint with h_init (0.9 / 0.1) + half_mul_project
    {
        float b0 = 0.f, b1 = 0.f, b2 = 0.f;
        if (act) {
            const float* hr = h_init + (size_t)i * D;
            b0 = hr[lane];
            b1 = hr[lane + 16];
            b2 = hr[lane + 32];
        }
        float sa = gsum(a0 * a0 + a1 * a1 + a2 * a2);
        float sb = gsum(b0 * b0 + b1 * b1 + b2 * b2);
        float ga = 2.0f / fmaxf(1.0f - sa, F_EPS);
        float gb = 2.0f / fmaxf(1.0f - sb, F_EPS);
        const float wa = 0.9f, wb = 0.1f;
        float dinv = 1.0f / clampabs(wa * (ga - 1.0f) + wb * (gb - 1.0f));
        float ca = wa * ga * dinv, cb = wb * gb * dinv;
        a0 = ca * a0 + cb * b0;
        a1 = ca * a1 + cb * b1;
        a2 = ca * a2 + cb * b2;
        float s = gsum(a0 * a0 + a1 * a1 + a2 * a2);
        float nrm = sqrtf(s);
        float ncl = fmaxf(nrm, F_EPS);
        float tt = tanhf(0.5f * artanh_c(ncl));
        float sc = tt / ncl;
        float rn = nrm * sc;
        if (rn > MAXNORM) sc *= MAXNORM / fmaxf(rn, F_EPS);
        a0 *= sc; a1 *= sc; a2 *= sc;
    }

    // stage a to LDS for the row dots
    aLds[grp][lane]      = a0;
    aLds[grp][lane + 16] = a1;
    aLds[grp][lane + 32] = a2;
    __syncthreads();

    float sa2 = gsum(a0 * a0 + a1 * a1 + a2 * a2);
    float xn = fmaxf(sqrtf(sa2), F_EPS);

    // ---- 3) matvec: 3 rows per lane, accs stay in registers
    const float* av = aLds[grp];
    const float* w0 = &Ws[lane * WSTR];
    const float* w1 = &Ws[(lane + 16) * WSTR];
    const float* w2 = &Ws[(lane + 32) * WSTR];
    float acc0 = 0.f, acc1 = 0.f, acc2 = 0.f;
#pragma unroll
    for (int k = 0; k < D; ++k) {
        float ak = av[k];
        acc0 = fmaf(w0[k], ak, acc0);
        acc1 = fmaf(w1[k], ak, acc1);
        acc2 = fmaf(w2[k], ak, acc2);
    }
    float bl0 = bs[lane], bl1 = bs[lane + 16], bl2 = bs[lane + 32];
    float smx = gsum(acc0 * acc0 + acc1 * acc1 + acc2 * acc2);
    float xyr = gsum(acc0 * bl0 + acc1 * bl1 + acc2 * bl2);
    float bn2 = gsum(bl0 * bl0 + bl1 * bl1 + bl2 * bl2);

    float mxnr = sqrtf(smx);
    float mxn = fmaxf(mxnr, F_EPS);
    float tt = tanhf((mxn / xn) * artanh_c(xn));
    float sc = tt / mxn;
    float rn = mxnr * sc;
    if (rn > MAXNORM) sc *= MAXNORM / fmaxf(rn, F_EPS);

    float bn  = fmaxf(sqrtf(bn2), F_EPS);
    float ebs = tanhf(bn) / bn;
    float y2  = ebs * ebs * bn2;

    float x2 = sc * sc * smx;
    float xy = sc * ebs * xyr;
    float c1 = 1.0f + 2.0f * xy + y2;
    float c2 = 1.0f - x2;
    float dn3 = 1.0f / fmaxf(1.0f + 2.0f * xy + x2 * y2, F_EPS);

    float s3 = dn3 * dn3 * (c1 * c1 * sc * sc * smx
                            + 2.0f * c1 * c2 * sc * ebs * xyr
                            + c2 * c2 * ebs * ebs * bn2);
    float nrm3 = sqrtf(s3);
    float fp = (nrm3 > MAXNORM) ? (MAXNORM / fmaxf(nrm3, F_EPS)) : 1.0f;

    float CA = c1 * sc * dn3 * fp;
    float CB = c2 * ebs * dn3 * fp;

    if (act) {
        float* orow = out + (size_t)i * D;
        orow[lane]      = fmaf(CA, acc0, CB * bl0);
        orow[lane + 16] = fmaf(CA, acc1, CB * bl1);
        orow[lane + 32] = fmaf(CA, acc2, CB * bl2);
    }
}

extern "C" void kernel_launch(void* const* d_in, const int* in_sizes, int n_in,
                              void* d_out, int out_size, void* d_ws, size_t ws_size,
                              hipStream_t stream)
{
    const float* x      = (const float*)d_in[0];
    const float* h_init = (const float*)d_in[1];
    const float* edge_w = (const float*)d_in[2];
    const float* W      = (const float*)d_in[3];
    const float* bias   = (const float*)d_in[4];
    const int*   esrc   = (const int*)d_in[5];
    const int*   edst   = (const int*)d_in[6];
    float* out = (float*)d_out;

    int n = in_sizes[0] / D;
    int E = in_sizes[2];
    int nb = (n + SPAN - 1) >> SHIFT;

    // ws layout
    char* p = (char*)d_ws;
    float* gam    = (float*)p;             p += (size_t)n * 4;
    float* den    = (float*)p;             p += (size_t)n * 4;
    int*   ghist  = (int*)p;               p += (size_t)nb * 4;
    int*   gstart = (int*)p;               p += (size_t)(nb + 1) * 4;
    int*   gcur   = (int*)p;               p += (size_t)nb * 4;
    int*   starts = (int*)p;               p += (size_t)(n + 1) * 4;
    p = (char*)(((uintptr_t)p + 15) & ~(uintptr_t)15);   // align 16
    int2*  seg    = (int2*)p;              p += (size_t)E * 8;
    int2*  seg2   = (int2*)p;              p += (size_t)E * 8;
    size_t need1 = (size_t)(p - (char*)d_ws);
    ushort4* ybf = (ushort4*)seg;
    bool ybf_fits = ((size_t)E * 8 >= (size_t)n * D * 2);

    k_gamma<<<(n + 255) / 256, 256, 0, stream>>>(x, gam, ghist, n, nb);

    bool shape_ok = (nb <= 1024) && (n < (1 << 24));
    if (shape_ok && ybf_fits && need1 <= ws_size) {
        int pb = (E + PCH - 1) / PCH;
        k_hist<<<pb, PTH, 0, stream>>>(edst, ghist, E, nb);
        k_scanb<<<1, 1024, 0, stream>>>(ghist, gstart, gcur, nb, E);
        k_part<<<pb, PTH, 0, stream>>>(esrc, edst, edge_w, gam, gcur, seg, E, nb);
        k_sortb<<<nb, 256, 0, stream>>>(seg, gstart, starts, seg2, n, E);
        long long tot = (long long)n * DQ;
        int gg = (int)((tot + 255) / 256);
        k_prep<<<gg, 256, 0, stream>>>(x, gam, ybf, n);
        k_gather<<<gg, 256, 0, stream>>>(ybf, starts, seg2, out, den, n, E);
    } else {
        k_init_atomic<<<(n + 255) / 256, 256, 0, stream>>>(den, out, n);
        long long tot = (long long)E * DQ;
        k_edge_atomic<<<(int)((tot + 255) / 256), 256, 0, stream>>>(x, gam, esrc, edst, edge_w, out, den, E);
    }

    k_node<<<(n + NPB - 1) / NPB, 256, 0, stream>>>(out, den, h_init, W, bias, n);
}

// Round 15
// 150.086 us; speedup vs baseline: 1.0950x; 1.0439x over previous
//
#include <hip/hip_runtime.h>
#include <math.h>

#define D  48
#define DQ 12        // D/4
#define SPAN 128     // nodes per bucket
#define SHIFT 7      // log2(SPAN)
#define PCH  8192    // edges per hist/partition block
#define PTH  512     // threads for hist/part
#define NPB  16      // nodes per k_node block (16 threads/node)
#define WSTR 52      // Ws row stride (16B-aligned, conflict-free float4 reads)

constexpr float F_EPS   = 1e-15f;
constexpr float MAXNORM = 1.0f - 1e-5f;

__device__ __forceinline__ float artanh_c(float x) {
    x = fminf(x, 1.0f - 1e-7f);
    x = fmaxf(x, -1.0f + 1e-7f);
    return atanhf(x);
}

__device__ __forceinline__ float clampabs(float x) {
    return (x >= 0.0f) ? fmaxf(x, 1e-10f) : fminf(x, -1e-10f);
}

__device__ __forceinline__ unsigned short f2bf(float f) {
    unsigned u = __float_as_uint(f);
    u += 0x7FFFu + ((u >> 16) & 1u);
    return (unsigned short)(u >> 16);
}

__device__ __forceinline__ float bf2f(unsigned short u) {
    return __uint_as_float(((unsigned)u) << 16);
}

// fast tanh for x>=0 via hw exp: 1 - 2/(e^2x+1); e=inf -> 1 (overflow-safe)
__device__ __forceinline__ float fast_tanh(float x) {
    float e = __expf(2.0f * x);
    return 1.0f - __fdividef(2.0f, e + 1.0f);
}
// fast atanh for 0<=x<1 via hw log
__device__ __forceinline__ float fast_atanh(float x) {
    x = fminf(x, 1.0f - 1e-7f);
    return 0.5f * __logf(__fdividef(1.0f + x, 1.0f - x));
}

// ---------- per-node gamma + zero bucket histogram ----------
__global__ void k_gamma(const float* __restrict__ x, float* __restrict__ gam,
                        int* __restrict__ ghist, int n, int nb)
{
    int i = blockIdx.x * blockDim.x + threadIdx.x;
    if (i < nb) ghist[i] = 0;
    if (i >= n) return;
    const float4* xr = reinterpret_cast<const float4*>(x) + (size_t)i * DQ;
    float s = 0.0f;
#pragma unroll
    for (int q = 0; q < DQ; ++q) {
        float4 v = xr[q];
        s += v.x * v.x + v.y * v.y + v.z * v.z + v.w * v.w;
    }
    gam[i] = 2.0f / fmaxf(1.0f - s, F_EPS);
}

// ---------- bucket histogram (LDS-staged, unrolled) ----------
__global__ __launch_bounds__(PTH) void k_hist(const int* __restrict__ dst,
                                              int* __restrict__ ghist, int E, int nb)
{
    __shared__ int h[1024];
    int t = threadIdx.x;
    for (int i = t; i < 1024; i += PTH) h[i] = 0;
    __syncthreads();
    int base = blockIdx.x * PCH;
#pragma unroll 4
    for (int k = 0; k < PCH / PTH; ++k) {
        int i = base + k * PTH + t;
        if (i < E) {
            unsigned b = ((unsigned)dst[i]) >> SHIFT;
            if (b < 1024u) atomicAdd(&h[b], 1);
        }
    }
    __syncthreads();
    for (int i = t; i < nb; i += PTH) {
        int c = h[i];
        if (c) atomicAdd(&ghist[i], c);
    }
}

// ---------- exclusive scan of bucket counts (single block, nb <= 1024) ----------
__global__ __launch_bounds__(1024) void k_scanb(const int* __restrict__ ghist,
                                                int* __restrict__ gstart,
                                                int* __restrict__ gcur, int nb, int E)
{
    __shared__ int sh[1024];
    int t = threadIdx.x;
    int v = (t < nb) ? ghist[t] : 0;
    sh[t] = v;
    __syncthreads();
    for (int off = 1; off < 1024; off <<= 1) {
        int a = sh[t];
        int b = (t >= off) ? sh[t - off] : 0;
        __syncthreads();
        sh[t] = a + b;
        __syncthreads();
    }
    if (t < nb) { int s = sh[t] - v; gstart[t] = s; gcur[t] = s; }
    if (t == 0) gstart[nb] = E;
}

// ---------- partition: bucket-burst records with packed bf16 weights ----------
__global__ __launch_bounds__(PTH) void k_part(const int* __restrict__ src,
                                              const int* __restrict__ dst,
                                              const float* __restrict__ w,
                                              const float* __restrict__ gam,
                                              int* __restrict__ gcur,
                                              int2* __restrict__ seg, int E, int nb)
{
    __shared__ int hist[1024];
    __shared__ int base_[1024];
    __shared__ int lcur[1024];
    int t = threadIdx.x;
    for (int i = t; i < 1024; i += PTH) { hist[i] = 0; base_[i] = 0; lcur[i] = 0; }
    __syncthreads();
    int b0 = blockIdx.x * PCH;
#pragma unroll 4
    for (int k = 0; k < PCH / PTH; ++k) {
        int i = b0 + k * PTH + t;
        if (i < E) {
            unsigned b = ((unsigned)dst[i]) >> SHIFT;
            if (b < 1024u) atomicAdd(&hist[b], 1);
        }
    }
    __syncthreads();
    for (int i = t; i < nb; i += PTH) {
        int c = hist[i];
        if (c) base_[i] = atomicAdd(&gcur[i], c);
    }
    __syncthreads();
#pragma unroll 4
    for (int k = 0; k < PCH / PTH; ++k) {
        int i = b0 + k * PTH + t;
        if (i < E) {
            int d = dst[i];
            unsigned b = ((unsigned)d) >> SHIFT;
            if (b < 1024u) {
                int s = src[i];
                float wv = w[i];
                float g  = gam[s];
                unsigned short wb  = f2bf(wv);
                unsigned short wdb = f2bf(fabsf(wv) * (g - 1.0f));
                int pos = base_[b] + atomicAdd(&lcur[b], 1);
                if (pos >= 0 && pos < E) {
                    int2 r;
                    r.x = ((d & (SPAN - 1)) << 24) | (s & 0xFFFFFF);
                    r.y = ((unsigned)wb << 16) | wdb;
                    seg[pos] = r;
                }
            }
        }
    }
}

// ---------- per-bucket LDS counting sort -> exact per-node order + starts ----------
__global__ __launch_bounds__(256) void k_sortb(
    const int2* __restrict__ seg, const int* __restrict__ gstart,
    int* __restrict__ starts, int2* __restrict__ seg2, int n, int E)
{
    __shared__ int hist[SPAN];
    __shared__ int sb[SPAN];
    __shared__ int cur[SPAN];
    int b = blockIdx.x;
    int t = threadIdx.x;
    if (b == 0 && t == 0) starts[n] = E;
    int segL = gstart[b], segR = gstart[b + 1];
    if (segL < 0) segL = 0;
    if (segR > E) segR = E;
    if (t < SPAN) hist[t] = 0;
    __syncthreads();
    {
        int j = segL + t;
        for (; j + 768 < segR; j += 1024) {
            unsigned d0 = ((unsigned)seg[j      ].x) >> 24;
            unsigned d1 = ((unsigned)seg[j + 256].x) >> 24;
            unsigned d2 = ((unsigned)seg[j + 512].x) >> 24;
            unsigned d3 = ((unsigned)seg[j + 768].x) >> 24;
            atomicAdd(&hist[d0], 1);
            atomicAdd(&hist[d1], 1);
            atomicAdd(&hist[d2], 1);
            atomicAdd(&hist[d3], 1);
        }
        for (; j < segR; j += 256) {
            unsigned dl = ((unsigned)seg[j].x) >> 24;
            atomicAdd(&hist[dl], 1);
        }
    }
    __syncthreads();
    if (t < SPAN) sb[t] = hist[t];
    __syncthreads();
    for (int off = 1; off < SPAN; off <<= 1) {
        int a = 0;
        if (t < SPAN) { a = sb[t]; if (t >= off) a += sb[t - off]; }
        __syncthreads();
        if (t < SPAN) sb[t] = a;
        __syncthreads();
    }
    if (t < SPAN) {
        int ls = sb[t] - hist[t];
        cur[t] = segL + ls;
        int node = b * SPAN + t;
        if (node < n) starts[node] = segL + ls;
    }
    __syncthreads();
    {
        int j = segL + t;
        for (; j + 768 < segR; j += 1024) {
            int2 r0 = seg[j      ];
            int2 r1 = seg[j + 256];
            int2 r2 = seg[j + 512];
            int2 r3 = seg[j + 768];
            int p0 = atomicAdd(&cur[((unsigned)r0.x) >> 24], 1);
            int p1 = atomicAdd(&cur[((unsigned)r1.x) >> 24], 1);
            int p2 = atomicAdd(&cur[((unsigned)r2.x) >> 24], 1);
            int p3 = atomicAdd(&cur[((unsigned)r3.x) >> 24], 1);
            if (p0 >= 0 && p0 < E) seg2[p0] = make_int2(r0.x & 0xFFFFFF, r0.y);
            if (p1 >= 0 && p1 < E) seg2[p1] = make_int2(r1.x & 0xFFFFFF, r1.y);
            if (p2 >= 0 && p2 < E) seg2[p2] = make_int2(r2.x & 0xFFFFFF, r2.y);
            if (p3 >= 0 && p3 < E) seg2[p3] = make_int2(r3.x & 0xFFFFFF, r3.y);
        }
        for (; j < segR; j += 256) {
            int2 r = seg[j];
            int pos = atomicAdd(&cur[((unsigned)r.x) >> 24], 1);
            if (pos >= 0 && pos < E) seg2[pos] = make_int2(r.x & 0xFFFFFF, r.y);
        }
    }
}

// ---------- precompute ybf[s] = bf16(gam[s] * x[s]) into dead seg buffer ----------
__global__ __launch_bounds__(256) void k_prep(const float* __restrict__ x,
                                              const float* __restrict__ gam,
                                              ushort4* __restrict__ ybf, int n)
{
    long long t = (long long)blockIdx.x * blockDim.x + threadIdx.x;
    int node = (int)(t / DQ);
    if (node >= n) return;
    int part = (int)(t % DQ);
    float g = gam[node];
    float4 v = reinterpret_cast<const float4*>(x)[(size_t)node * DQ + part];
    ushort4 o;
    o.x = f2bf(v.x * g);
    o.y = f2bf(v.y * g);
    o.z = f2bf(v.z * g);
    o.w = f2bf(v.w * g);
    ybf[(size_t)node * DQ + part] = o;
}

// ---------- gather: 12 lanes/node, single random stream, 4-wide pipeline ----------
__global__ __launch_bounds__(256) void k_gather(
    const ushort4* __restrict__ ybf,
    const int* __restrict__ starts,
    const int2* __restrict__ srec,
    float* __restrict__ num, float* __restrict__ den, int n, int E)
{
    long long t = (long long)blockIdx.x * blockDim.x + threadIdx.x;
    int node = (int)(t / DQ);
    if (node >= n) return;
    int part = (int)(t % DQ);
    int j0 = starts[node], j1 = starts[node + 1];
    if (j0 < 0) j0 = 0;
    if (j1 > E) j1 = E;
    float4 acc = make_float4(0.f, 0.f, 0.f, 0.f);
    float dacc = 0.f;
    int j = j0;
    for (; j + 3 < j1; j += 4) {
        int2 r0 = srec[j];
        int2 r1 = srec[j + 1];
        int2 r2 = srec[j + 2];
        int2 r3 = srec[j + 3];
        ushort4 a0 = ybf[(size_t)(r0.x) * DQ + part];
        ushort4 a1 = ybf[(size_t)(r1.x) * DQ + part];
        ushort4 a2 = ybf[(size_t)(r2.x) * DQ + part];
        ushort4 a3 = ybf[(size_t)(r3.x) * DQ + part];
        float w0 = bf2f((unsigned short)(((unsigned)r0.y) >> 16));
        float w1 = bf2f((unsigned short)(((unsigned)r1.y) >> 16));
        float w2 = bf2f((unsigned short)(((unsigned)r2.y) >> 16));
        float w3 = bf2f((unsigned short)(((unsigned)r3.y) >> 16));
        acc.x = fmaf(w0, bf2f(a0.x), acc.x);
        acc.y = fmaf(w0, bf2f(a0.y), acc.y);
        acc.z = fmaf(w0, bf2f(a0.z), acc.z);
        acc.w = fmaf(w0, bf2f(a0.w), acc.w);
        acc.x = fmaf(w1, bf2f(a1.x), acc.x);
        acc.y = fmaf(w1, bf2f(a1.y), acc.y);
        acc.z = fmaf(w1, bf2f(a1.z), acc.z);
        acc.w = fmaf(w1, bf2f(a1.w), acc.w);
        acc.x = fmaf(w2, bf2f(a2.x), acc.x);
        acc.y = fmaf(w2, bf2f(a2.y), acc.y);
        acc.z = fmaf(w2, bf2f(a2.z), acc.z);
        acc.w = fmaf(w2, bf2f(a2.w), acc.w);
        acc.x = fmaf(w3, bf2f(a3.x), acc.x);
        acc.y = fmaf(w3, bf2f(a3.y), acc.y);
        acc.z = fmaf(w3, bf2f(a3.z), acc.z);
        acc.w = fmaf(w3, bf2f(a3.w), acc.w);
        dacc += bf2f((unsigned short)(((unsigned)r0.y) & 0xFFFF))
              + bf2f((unsigned short)(((unsigned)r1.y) & 0xFFFF))
              + bf2f((unsigned short)(((unsigned)r2.y) & 0xFFFF))
              + bf2f((unsigned short)(((unsigned)r3.y) & 0xFFFF));
    }
    for (; j < j1; ++j) {
        int2 r0 = srec[j];
        ushort4 a0 = ybf[(size_t)(r0.x) * DQ + part];
        float w0 = bf2f((unsigned short)(((unsigned)r0.y) >> 16));
        acc.x = fmaf(w0, bf2f(a0.x), acc.x);
        acc.y = fmaf(w0, bf2f(a0.y), acc.y);
        acc.z = fmaf(w0, bf2f(a0.z), acc.z);
        acc.w = fmaf(w0, bf2f(a0.w), acc.w);
        dacc += bf2f((unsigned short)(((unsigned)r0.y) & 0xFFFF));
    }
    reinterpret_cast<float4*>(num)[(size_t)node * DQ + part] = acc;
    if (part == 0) den[node] = dacc;
}

// ---------- fallback: atomic edge scatter ----------
__global__ void k_init_atomic(float* __restrict__ den, float* __restrict__ num, int n)
{
    int i = blockIdx.x * blockDim.x + threadIdx.x;
    if (i >= n) return;
    den[i] = 0.0f;
    float4* nr = reinterpret_cast<float4*>(num) + (size_t)i * DQ;
    float4 z = make_float4(0.f, 0.f, 0.f, 0.f);
#pragma unroll
    for (int q = 0; q < DQ; ++q) nr[q] = z;
}

__global__ void k_edge_atomic(const float* __restrict__ x, const float* __restrict__ gam,
                              const int* __restrict__ src, const int* __restrict__ dst,
                              const float* __restrict__ w,
                              float* __restrict__ num, float* __restrict__ den, int E)
{
    long long t = (long long)blockIdx.x * blockDim.x + threadIdx.x;
    int e = (int)(t / DQ);
    if (e >= E) return;
    int part = (int)(t % DQ);
    int s = src[e];
    int d = dst[e];
    float we = w[e];
    float g  = gam[s];
    float4 xv = reinterpret_cast<const float4*>(x)[(size_t)s * DQ + part];
    float c = we * g;
    float* np_ = num + (size_t)d * D + part * 4;
    atomicAdd(np_ + 0, c * xv.x);
    atomicAdd(np_ + 1, c * xv.y);
    atomicAdd(np_ + 2, c * xv.z);
    atomicAdd(np_ + 3, c * xv.w);
    if (part == 0) atomicAdd(den + d, fabsf(we) * (g - 1.0f));
}

// k_node v6: 16 threads/node (R14, occupancy fix) + instruction diet:
//  - tanh(0.5*atanh(m)) = m/(1+sqrt(1-m^2))  -> half_mul_project has ZERO
//    transcendentals (pure sqrt+div)
//  - remaining tanh/atanh via hw __expf/__logf (overflow-safe forms)
//  - matvec LDS reads vectorized to float4 (192 -> 48 ds ops/thread);
//    WSTR=52: 16 lanes x 208B stride covers all 32 banks 2x (free)
//  - post-projection norms known in scalar -> 2 fewer shuffle-reductions
__global__ __launch_bounds__(256) void k_node(
    float* __restrict__ out,
    const float* __restrict__ den,
    const float* __restrict__ h_init,
    const float* __restrict__ Wm,
    const float* __restrict__ bias, int n)
{
    __shared__ float Ws[D * WSTR];
    __shared__ float bs[D];
    __shared__ float aLds[NPB][D];
    int t = threadIdx.x;
    for (int k = t; k < D * D; k += 256) Ws[(k / D) * WSTR + (k % D)] = Wm[k];
    if (t < D) bs[t] = bias[t];
    __syncthreads();

    int grp = t >> 4;
    int lane = t & 15;
    int i = blockIdx.x * NPB + grp;
    bool act = (i < n);

    auto gsum = [](float v) {
        v += __shfl_xor(v, 1, 16);
        v += __shfl_xor(v, 2, 16);
        v += __shfl_xor(v, 4, 16);
        v += __shfl_xor(v, 8, 16);
        return v;
    };

    // combined mobius_scalar_mul(0.5)+project scale from s = ||v||^2
    auto hmp_scale = [](float s) {
        float nrm = sqrtf(s);
        float ncl = fmaxf(nrm, F_EPS);
        float m = fminf(ncl, 1.0f - 1e-7f);
        float sc = __fdividef(__fdividef(m, ncl),
                              1.0f + sqrtf(fmaxf(1.0f - m * m, 0.0f)));
        float rn = nrm * sc;
        if (rn > MAXNORM) sc *= MAXNORM / fmaxf(rn, F_EPS);
        return sc;
    };

    // ---- 1) a = num/clamp_abs(den); half-mul+project
    float a0 = 0.f, a1 = 0.f, a2 = 0.f;
    if (act) {
        float dinv = 1.0f / clampabs(den[i]);
        const float* nr = out + (size_t)i * D;
        a0 = nr[lane] * dinv;
        a1 = nr[lane + 16] * dinv;
        a2 = nr[lane + 32] * dinv;
    }
    float s1 = gsum(a0 * a0 + a1 * a1 + a2 * a2);
    float sc1 = hmp_scale(s1);
    a0 *= sc1; a1 *= sc1; a2 *= sc1;
    float sa = s1 * sc1 * sc1;              // ||a||^2 after step 1 (scalar)

    // ---- 2) pair midpoint with h_init (0.9 / 0.1) + half-mul+project
    float s2, sc2;
    {
        float b0 = 0.f, b1 = 0.f, b2 = 0.f;
        if (act) {
            const float* hr = h_init + (size_t)i * D;
            b0 = hr[lane];
            b1 = hr[lane + 16];
            b2 = hr[lane + 32];
        }
        float sb = gsum(b0 * b0 + b1 * b1 + b2 * b2);
        float ga = 2.0f / fmaxf(1.0f - sa, F_EPS);
        float gb = 2.0f / fmaxf(1.0f - sb, F_EPS);
        const float wa = 0.9f, wb = 0.1f;
        float dinv = 1.0f / clampabs(wa * (ga - 1.0f) + wb * (gb - 1.0f));
        float ca = wa * ga * dinv, cb = wb * gb * dinv;
        a0 = ca * a0 + cb * b0;
        a1 = ca * a1 + cb * b1;
        a2 = ca * a2 + cb * b2;
        s2 = gsum(a0 * a0 + a1 * a1 + a2 * a2);
        sc2 = hmp_scale(s2);
        a0 *= sc2; a1 *= sc2; a2 *= sc2;
    }
    float xn = fmaxf(sqrtf(s2) * sc2, F_EPS);   // ||a|| after step 2 (scalar)

    // stage a to LDS for the row dots
    aLds[grp][lane]      = a0;
    aLds[grp][lane + 16] = a1;
    aLds[grp][lane + 32] = a2;
    __syncthreads();

    // ---- 3) matvec: 3 rows per lane, float4 LDS reads, accs in registers
    const float4* av4 = reinterpret_cast<const float4*>(aLds[grp]);
    const float4* w04 = reinterpret_cast<const float4*>(&Ws[lane * WSTR]);
    const float4* w14 = reinterpret_cast<const float4*>(&Ws[(lane + 16) * WSTR]);
    const float4* w24 = reinterpret_cast<const float4*>(&Ws[(lane + 32) * WSTR]);
    float acc0 = 0.f, acc1 = 0.f, acc2 = 0.f;
#pragma unroll
    for (int kq = 0; kq < DQ; ++kq) {
        float4 a4 = av4[kq];
        float4 x0 = w04[kq];
        float4 x1 = w14[kq];
        float4 x2 = w24[kq];
        acc0 = fmaf(x0.x, a4.x, acc0); acc0 = fmaf(x0.y, a4.y, acc0);
        acc0 = fmaf(x0.z, a4.z, acc0); acc0 = fmaf(x0.w, a4.w, acc0);
        acc1 = fmaf(x1.x, a4.x, acc1); acc1 = fmaf(x1.y, a4.y, acc1);
        acc1 = fmaf(x1.z, a4.z, acc1); acc1 = fmaf(x1.w, a4.w, acc1);
        acc2 = fmaf(x2.x, a4.x, acc2); acc2 = fmaf(x2.y, a4.y, acc2);
        acc2 = fmaf(x2.z, a4.z, acc2); acc2 = fmaf(x2.w, a4.w, acc2);
    }
    float bl0 = bs[lane], bl1 = bs[lane + 16], bl2 = bs[lane + 32];
    float smx = gsum(acc0 * acc0 + acc1 * acc1 + acc2 * acc2);
    float xyr = gsum(acc0 * bl0 + acc1 * bl1 + acc2 * bl2);
    float bn2 = gsum(bl0 * bl0 + bl1 * bl1 + bl2 * bl2);

    float mxnr = sqrtf(smx);
    float mxn = fmaxf(mxnr, F_EPS);
    float tt = fast_tanh(__fdividef(mxn, xn) * fast_atanh(xn));
    float sc = __fdividef(tt, mxn);
    float rn = mxnr * sc;
    if (rn > MAXNORM) sc *= MAXNORM / fmaxf(rn, F_EPS);

    float bn  = fmaxf(sqrtf(bn2), F_EPS);
    float ebs = __fdividef(fast_tanh(bn), bn);
    float y2  = ebs * ebs * bn2;

    float x2v = sc * sc * smx;
    float xy = sc * ebs * xyr;
    float c1 = 1.0f + 2.0f * xy + y2;
    float c2 = 1.0f - x2v;
    float dn3 = 1.0f / fmaxf(1.0f + 2.0f * xy + x2v * y2, F_EPS);

    float s3 = dn3 * dn3 * (c1 * c1 * sc * sc * smx
                            + 2.0f * c1 * c2 * sc * ebs * xyr
                            + c2 * c2 * ebs * ebs * bn2);
    float nrm3 = sqrtf(s3);
    float fp = (nrm3 > MAXNORM) ? (MAXNORM / fmaxf(nrm3, F_EPS)) : 1.0f;

    float CA = c1 * sc * dn3 * fp;
    float CB = c2 * ebs * dn3 * fp;

    if (act) {
        float* orow = out + (size_t)i * D;
        orow[lane]      = fmaf(CA, acc0, CB * bl0);
        orow[lane + 16] = fmaf(CA, acc1, CB * bl1);
        orow[lane + 32] = fmaf(CA, acc2, CB * bl2);
    }
}

extern "C" void kernel_launch(void* const* d_in, const int* in_sizes, int n_in,
                              void* d_out, int out_size, void* d_ws, size_t ws_size,
                              hipStream_t stream)
{
    const float* x      = (const float*)d_in[0];
    const float* h_init = (const float*)d_in[1];
    const float* edge_w = (const float*)d_in[2];
    const float* W      = (const float*)d_in[3];
    const float* bias   = (const float*)d_in[4];
    const int*   esrc   = (const int*)d_in[5];
    const int*   edst   = (const int*)d_in[6];
    float* out = (float*)d_out;

    int n = in_sizes[0] / D;
    int E = in_sizes[2];
    int nb = (n + SPAN - 1) >> SHIFT;

    // ws layout
    char* p = (char*)d_ws;
    float* gam    = (float*)p;             p += (size_t)n * 4;
    float* den    = (float*)p;             p += (size_t)n * 4;
    int*   ghist  = (int*)p;               p += (size_t)nb * 4;
    int*   gstart = (int*)p;               p += (size_t)(nb + 1) * 4;
    int*   gcur   = (int*)p;               p += (size_t)nb * 4;
    int*   starts = (int*)p;               p += (size_t)(n + 1) * 4;
    p = (char*)(((uintptr_t)p + 15) & ~(uintptr_t)15);   // align 16
    int2*  seg    = (int2*)p;              p += (size_t)E * 8;
    int2*  seg2   = (int2*)p;              p += (size_t)E * 8;
    size_t need1 = (size_t)(p - (char*)d_ws);
    ushort4* ybf = (ushort4*)seg;
    bool ybf_fits = ((size_t)E * 8 >= (size_t)n * D * 2);

    k_gamma<<<(n + 255) / 256, 256, 0, stream>>>(x, gam, ghist, n, nb);

    bool shape_ok = (nb <= 1024) && (n < (1 << 24));
    if (shape_ok && ybf_fits && need1 <= ws_size) {
        int pb = (E + PCH - 1) / PCH;
        k_hist<<<pb, PTH, 0, stream>>>(edst, ghist, E, nb);
        k_scanb<<<1, 1024, 0, stream>>>(ghist, gstart, gcur, nb, E);
        k_part<<<pb, PTH, 0, stream>>>(esrc, edst, edge_w, gam, gcur, seg, E, nb);
        k_sortb<<<nb, 256, 0, stream>>>(seg, gstart, starts, seg2, n, E);
        long long tot = (long long)n * DQ;
        int gg = (int)((tot + 255) / 256);
        k_prep<<<gg, 256, 0, stream>>>(x, gam, ybf, n);
        k_gather<<<gg, 256, 0, stream>>>(ybf, starts, seg2, out, den, n, E);
    } else {
        k_init_atomic<<<(n + 255) / 256, 256, 0, stream>>>(den, out, n);
        long long tot = (long long)E * DQ;
        k_edge_atomic<<<(int)((tot + 255) / 256), 256, 0, stream>>>(x, gam, esrc, edst, edge_w, out, den, E);
    }

    k_node<<<(n + NPB - 1) / NPB, 256, 0, stream>>>(out, den, h_init, W, bias, n);
}

// Round 16
// 144.723 us; speedup vs baseline: 1.1356x; 1.0371x over previous
//
#include <hip/hip_runtime.h>
#include <math.h>

#define D  48
#define DQ 12        // D/4
#define SPAN 128     // nodes per bucket
#define SHIFT 7      // log2(SPAN)
#define PCH  4096    // edges per hist/partition block
#define PTH  512     // threads for hist/part
#define NPB  16      // nodes per k_fuse block (16 threads/node)
#define WSTR 52      // LDS row stride (16B-aligned, low-conflict float4 reads)
#define YROW 13      // ybf row: 12 x ushort4 bf16(g*x) + 1 slot (g-1 as fp32)

constexpr float F_EPS   = 1e-15f;
constexpr float MAXNORM = 1.0f - 1e-5f;

__device__ __forceinline__ float artanh_c(float x) {
    x = fminf(x, 1.0f - 1e-7f);
    x = fmaxf(x, -1.0f + 1e-7f);
    return atanhf(x);
}

__device__ __forceinline__ float clampabs(float x) {
    return (x >= 0.0f) ? fmaxf(x, 1e-10f) : fminf(x, -1e-10f);
}

__device__ __forceinline__ unsigned short f2bf(float f) {
    unsigned u = __float_as_uint(f);
    u += 0x7FFFu + ((u >> 16) & 1u);
    return (unsigned short)(u >> 16);
}

__device__ __forceinline__ float bf2f(unsigned short u) {
    return __uint_as_float(((unsigned)u) << 16);
}

__device__ __forceinline__ float gm1f(ushort4 a) {   // fp32 packed in .x/.y
    return __uint_as_float((unsigned)a.x | ((unsigned)a.y << 16));
}

// fast tanh for x>=0 via hw exp (overflow-safe); fast atanh for 0<=x<1
__device__ __forceinline__ float fast_tanh(float x) {
    float e = __expf(2.0f * x);
    return 1.0f - __fdividef(2.0f, e + 1.0f);
}
__device__ __forceinline__ float fast_atanh(float x) {
    x = fminf(x, 1.0f - 1e-7f);
    return 0.5f * __logf(__fdividef(1.0f + x, 1.0f - x));
}

// ---------- per-node gamma + zero bucket histogram ----------
__global__ void k_gamma(const float* __restrict__ x, float* __restrict__ gam,
                        int* __restrict__ ghist, int n, int nb)
{
    int i = blockIdx.x * blockDim.x + threadIdx.x;
    if (i < nb) ghist[i] = 0;
    if (i >= n) return;
    const float4* xr = reinterpret_cast<const float4*>(x) + (size_t)i * DQ;
    float s = 0.0f;
#pragma unroll
    for (int q = 0; q < DQ; ++q) {
        float4 v = xr[q];
        s += v.x * v.x + v.y * v.y + v.z * v.z + v.w * v.w;
    }
    gam[i] = 2.0f / fmaxf(1.0f - s, F_EPS);
}

// ---------- bucket histogram (LDS-staged) ----------
__global__ __launch_bounds__(PTH) void k_hist(const int* __restrict__ dst,
                                              int* __restrict__ ghist, int E, int nb)
{
    __shared__ int h[1024];
    int t = threadIdx.x;
    for (int i = t; i < 1024; i += PTH) h[i] = 0;
    __syncthreads();
    int base = blockIdx.x * PCH;
#pragma unroll
    for (int k = 0; k < PCH / PTH; ++k) {
        int i = base + k * PTH + t;
        if (i < E) {
            unsigned b = ((unsigned)dst[i]) >> SHIFT;
            if (b < 1024u) atomicAdd(&h[b], 1);
        }
    }
    __syncthreads();
    for (int i = t; i < nb; i += PTH) {
        int c = h[i];
        if (c) atomicAdd(&ghist[i], c);
    }
}

// ---------- exclusive scan of bucket counts (single block, nb <= 1024) ----------
__global__ __launch_bounds__(1024) void k_scanb(const int* __restrict__ ghist,
                                                int* __restrict__ gstart,
                                                int* __restrict__ gcur, int nb, int E)
{
    __shared__ int sh[1024];
    int t = threadIdx.x;
    int v = (t < nb) ? ghist[t] : 0;
    sh[t] = v;
    __syncthreads();
    for (int off = 1; off < 1024; off <<= 1) {
        int a = sh[t];
        int b = (t >= off) ? sh[t - off] : 0;
        __syncthreads();
        sh[t] = a + b;
        __syncthreads();
    }
    if (t < nb) { int s = sh[t] - v; gstart[t] = s; gcur[t] = s; }
    if (t == 0) gstart[nb] = E;
}

// ---------- partition (pure streaming — no gam read; fp32 w in record) ----------
__global__ __launch_bounds__(PTH) void k_part(const int* __restrict__ src,
                                              const int* __restrict__ dst,
                                              const float* __restrict__ w,
                                              int* __restrict__ gcur,
                                              int2* __restrict__ seg, int E, int nb)
{
    __shared__ int hist[1024];
    __shared__ int base_[1024];
    __shared__ int lcur[1024];
    int t = threadIdx.x;
    for (int i = t; i < 1024; i += PTH) { hist[i] = 0; base_[i] = 0; lcur[i] = 0; }
    __syncthreads();
    int b0 = blockIdx.x * PCH;
#pragma unroll
    for (int k = 0; k < PCH / PTH; ++k) {
        int i = b0 + k * PTH + t;
        if (i < E) {
            unsigned b = ((unsigned)dst[i]) >> SHIFT;
            if (b < 1024u) atomicAdd(&hist[b], 1);
        }
    }
    __syncthreads();
    for (int i = t; i < nb; i += PTH) {
        int c = hist[i];
        if (c) base_[i] = atomicAdd(&gcur[i], c);
    }
    __syncthreads();
#pragma unroll
    for (int k = 0; k < PCH / PTH; ++k) {
        int i = b0 + k * PTH + t;
        if (i < E) {
            int d = dst[i];
            unsigned b = ((unsigned)d) >> SHIFT;
            if (b < 1024u) {
                int pos = base_[b] + atomicAdd(&lcur[b], 1);
                if (pos >= 0 && pos < E) {
                    int2 r;
                    r.x = ((d & (SPAN - 1)) << 24) | (src[i] & 0xFFFFFF);
                    r.y = __float_as_int(w[i]);
                    seg[pos] = r;
                }
            }
        }
    }
}

// ---------- per-bucket LDS counting sort -> exact per-node order + starts ----------
__global__ __launch_bounds__(256) void k_sortb(
    const int2* __restrict__ seg, const int* __restrict__ gstart,
    int* __restrict__ starts, int2* __restrict__ seg2, int n, int E)
{
    __shared__ int hist[SPAN];
    __shared__ int sb[SPAN];
    __shared__ int cur[SPAN];
    int b = blockIdx.x;
    int t = threadIdx.x;
    if (b == 0 && t == 0) starts[n] = E;
    int segL = gstart[b], segR = gstart[b + 1];
    if (segL < 0) segL = 0;
    if (segR > E) segR = E;
    if (t < SPAN) hist[t] = 0;
    __syncthreads();
    {
        int j = segL + t;
        for (; j + 768 < segR; j += 1024) {
            unsigned d0 = ((unsigned)seg[j      ].x) >> 24;
            unsigned d1 = ((unsigned)seg[j + 256].x) >> 24;
            unsigned d2 = ((unsigned)seg[j + 512].x) >> 24;
            unsigned d3 = ((unsigned)seg[j + 768].x) >> 24;
            atomicAdd(&hist[d0], 1);
            atomicAdd(&hist[d1], 1);
            atomicAdd(&hist[d2], 1);
            atomicAdd(&hist[d3], 1);
        }
        for (; j < segR; j += 256) {
            unsigned dl = ((unsigned)seg[j].x) >> 24;
            atomicAdd(&hist[dl], 1);
        }
    }
    __syncthreads();
    if (t < SPAN) sb[t] = hist[t];
    __syncthreads();
    for (int off = 1; off < SPAN; off <<= 1) {
        int a = 0;
        if (t < SPAN) { a = sb[t]; if (t >= off) a += sb[t - off]; }
        __syncthreads();
        if (t < SPAN) sb[t] = a;
        __syncthreads();
    }
    if (t < SPAN) {
        int ls = sb[t] - hist[t];
        cur[t] = segL + ls;
        int node = b * SPAN + t;
        if (node < n) starts[node] = segL + ls;
    }
    __syncthreads();
    {
        int j = segL + t;
        for (; j + 768 < segR; j += 1024) {
            int2 r0 = seg[j      ];
            int2 r1 = seg[j + 256];
            int2 r2 = seg[j + 512];
            int2 r3 = seg[j + 768];
            int p0 = atomicAdd(&cur[((unsigned)r0.x) >> 24], 1);
            int p1 = atomicAdd(&cur[((unsigned)r1.x) >> 24], 1);
            int p2 = atomicAdd(&cur[((unsigned)r2.x) >> 24], 1);
            int p3 = atomicAdd(&cur[((unsigned)r3.x) >> 24], 1);
            if (p0 >= 0 && p0 < E) seg2[p0] = make_int2(r0.x & 0xFFFFFF, r0.y);
            if (p1 >= 0 && p1 < E) seg2[p1] = make_int2(r1.x & 0xFFFFFF, r1.y);
            if (p2 >= 0 && p2 < E) seg2[p2] = make_int2(r2.x & 0xFFFFFF, r2.y);
            if (p3 >= 0 && p3 < E) seg2[p3] = make_int2(r3.x & 0xFFFFFF, r3.y);
        }
        for (; j < segR; j += 256) {
            int2 r = seg[j];
            int pos = atomicAdd(&cur[((unsigned)r.x) >> 24], 1);
            if (pos >= 0 && pos < E) seg2[pos] = make_int2(r.x & 0xFFFFFF, r.y);
        }
    }
}

// ---------- k_prep: ybf rows of 13 ushort4: 12x bf16(g*x) + fp32(g-1) ----------
__global__ __launch_bounds__(256) void k_prep(const float* __restrict__ x,
                                              const float* __restrict__ gam,
                                              ushort4* __restrict__ ybf, int n)
{
    long long t = (long long)blockIdx.x * blockDim.x + threadIdx.x;
    int node = (int)(t / YROW);
    if (node >= n) return;
    int slot = (int)(t % YROW);
    float g = gam[node];
    ushort4 o;
    if (slot < 12) {
        float4 v = reinterpret_cast<const float4*>(x)[(size_t)node * DQ + slot];
        o.x = f2bf(v.x * g);
        o.y = f2bf(v.y * g);
        o.z = f2bf(v.z * g);
        o.w = f2bf(v.w * g);
    } else {
        unsigned u = __float_as_uint(g - 1.0f);
        o.x = (unsigned short)(u & 0xFFFFu);
        o.y = (unsigned short)(u >> 16);
        o.z = 0; o.w = 0;
    }
    ybf[(size_t)node * YROW + slot] = o;
}

// ---------- fused gather + node math: 16 lanes per node ----------
__global__ __launch_bounds__(256) void k_fuse(
    const ushort4* __restrict__ ybf,
    const int* __restrict__ starts,
    const int2* __restrict__ srec,
    const float* __restrict__ h_init,
    const float* __restrict__ Wm,
    const float* __restrict__ bias,
    float* __restrict__ out, int n, int E)
{
    __shared__ float Ws[D * WSTR];
    __shared__ float bs[D];
    __shared__ float aLds[NPB][WSTR];
    int t = threadIdx.x;
    for (int k = t; k < D * D; k += 256) Ws[(k / D) * WSTR + (k % D)] = Wm[k];
    if (t < D) bs[t] = bias[t];

    int grp = t >> 4;
    int lane = t & 15;
    int i = blockIdx.x * NPB + grp;
    bool act = (i < n);

    auto gsum = [](float v) {
        v += __shfl_xor(v, 1, 16);
        v += __shfl_xor(v, 2, 16);
        v += __shfl_xor(v, 4, 16);
        v += __shfl_xor(v, 8, 16);
        return v;
    };
    auto hmp_scale = [](float s) {     // tanh(0.5*atanh(m))/m with project
        float nrm = sqrtf(s);
        float ncl = fmaxf(nrm, F_EPS);
        float m = fminf(ncl, 1.0f - 1e-7f);
        float sc = __fdividef(__fdividef(m, ncl),
                              1.0f + sqrtf(fmaxf(1.0f - m * m, 0.0f)));
        float rn = nrm * sc;
        if (rn > MAXNORM) sc *= MAXNORM / fmaxf(rn, F_EPS);
        return sc;
    };

    // ---- gather phase: lanes 0-11 num fragments, lane 12 den (gamma slot)
    int j0 = 0, j1 = 0;
    if (act) {
        j0 = starts[i]; j1 = starts[i + 1];
        if (j0 < 0) j0 = 0;
        if (j1 > E) j1 = E;
    }
    int pp = (lane < 12) ? lane : 12;
    float4 acc = make_float4(0.f, 0.f, 0.f, 0.f);
    float dacc = 0.f;
    int j = j0;
    for (; j + 3 < j1; j += 4) {
        int2 r0 = srec[j];
        int2 r1 = srec[j + 1];
        int2 r2 = srec[j + 2];
        int2 r3 = srec[j + 3];
        ushort4 a0 = ybf[(size_t)r0.x * YROW + pp];
        ushort4 a1 = ybf[(size_t)r1.x * YROW + pp];
        ushort4 a2 = ybf[(size_t)r2.x * YROW + pp];
        ushort4 a3 = ybf[(size_t)r3.x * YROW + pp];
        float w0 = __int_as_float(r0.y);
        float w1 = __int_as_float(r1.y);
        float w2 = __int_as_float(r2.y);
        float w3 = __int_as_float(r3.y);
        if (lane < 12) {
            acc.x = fmaf(w0, bf2f(a0.x), acc.x);
            acc.y = fmaf(w0, bf2f(a0.y), acc.y);
            acc.z = fmaf(w0, bf2f(a0.z), acc.z);
            acc.w = fmaf(w0, bf2f(a0.w), acc.w);
            acc.x = fmaf(w1, bf2f(a1.x), acc.x);
            acc.y = fmaf(w1, bf2f(a1.y), acc.y);
            acc.z = fmaf(w1, bf2f(a1.z), acc.z);
            acc.w = fmaf(w1, bf2f(a1.w), acc.w);
            acc.x = fmaf(w2, bf2f(a2.x), acc.x);
            acc.y = fmaf(w2, bf2f(a2.y), acc.y);
            acc.z = fmaf(w2, bf2f(a2.z), acc.z);
            acc.w = fmaf(w2, bf2f(a2.w), acc.w);
            acc.x = fmaf(w3, bf2f(a3.x), acc.x);
            acc.y = fmaf(w3, bf2f(a3.y), acc.y);
            acc.z = fmaf(w3, bf2f(a3.z), acc.z);
            acc.w = fmaf(w3, bf2f(a3.w), acc.w);
        } else if (lane == 12) {
            dacc += fabsf(w0) * gm1f(a0) + fabsf(w1) * gm1f(a1)
                  + fabsf(w2) * gm1f(a2) + fabsf(w3) * gm1f(a3);
        }
    }
    for (; j < j1; ++j) {
        int2 r0 = srec[j];
        ushort4 a0 = ybf[(size_t)r0.x * YROW + pp];
        float w0 = __int_as_float(r0.y);
        if (lane < 12) {
            acc.x = fmaf(w0, bf2f(a0.x), acc.x);
            acc.y = fmaf(w0, bf2f(a0.y), acc.y);
            acc.z = fmaf(w0, bf2f(a0.z), acc.z);
            acc.w = fmaf(w0, bf2f(a0.w), acc.w);
        } else if (lane == 12) {
            dacc += fabsf(w0) * gm1f(a0);
        }
    }

    float dv = __shfl(dacc, 12, 16);           // broadcast den to group

    // redistribute num fragments (4p..4p+3) -> per-lane elems {l,l+16,l+32}
    if (lane < 12)
        reinterpret_cast<float4*>(&aLds[grp][0])[lane] = acc;
    __syncthreads();

    // ---- node math (R15 k_node v6, num/den from registers/LDS)
    float dinv = 1.0f / clampabs(dv);
    float a0 = aLds[grp][lane]      * dinv;
    float a1 = aLds[grp][lane + 16] * dinv;
    float a2 = aLds[grp][lane + 32] * dinv;

    float s1 = gsum(a0 * a0 + a1 * a1 + a2 * a2);
    float sc1 = hmp_scale(s1);
    a0 *= sc1; a1 *= sc1; a2 *= sc1;
    float sa = s1 * sc1 * sc1;

    float s2, sc2;
    {
        float b0 = 0.f, b1 = 0.f, b2 = 0.f;
        if (act) {
            const float* hr = h_init + (size_t)i * D;
            b0 = hr[lane];
            b1 = hr[lane + 16];
            b2 = hr[lane + 32];
        }
        float sb = gsum(b0 * b0 + b1 * b1 + b2 * b2);
        float ga = 2.0f / fmaxf(1.0f - sa, F_EPS);
        float gb = 2.0f / fmaxf(1.0f - sb, F_EPS);
        const float wa = 0.9f, wb = 0.1f;
        float dinv2 = 1.0f / clampabs(wa * (ga - 1.0f) + wb * (gb - 1.0f));
        float ca = wa * ga * dinv2, cb = wb * gb * dinv2;
        a0 = ca * a0 + cb * b0;
        a1 = ca * a1 + cb * b1;
        a2 = ca * a2 + cb * b2;
        s2 = gsum(a0 * a0 + a1 * a1 + a2 * a2);
        sc2 = hmp_scale(s2);
        a0 *= sc2; a1 *= sc2; a2 *= sc2;
    }
    float xn = fmaxf(sqrtf(s2) * sc2, F_EPS);

    // restage projected a for the float4 matvec
    aLds[grp][lane]      = a0;
    aLds[grp][lane + 16] = a1;
    aLds[grp][lane + 32] = a2;
    __syncthreads();

    const float4* av4 = reinterpret_cast<const float4*>(&aLds[grp][0]);
    const float4* w04 = reinterpret_cast<const float4*>(&Ws[lane * WSTR]);
    const float4* w14 = reinterpret_cast<const float4*>(&Ws[(lane + 16) * WSTR]);
    const float4* w24 = reinterpret_cast<const float4*>(&Ws[(lane + 32) * WSTR]);
    float acc0 = 0.f, acc1 = 0.f, acc2 = 0.f;
#pragma unroll
    for (int kq = 0; kq < DQ; ++kq) {
        float4 a4 = av4[kq];
        float4 x0 = w04[kq];
        float4 x1 = w14[kq];
        float4 x2 = w24[kq];
        acc0 = fmaf(x0.x, a4.x, acc0); acc0 = fmaf(x0.y, a4.y, acc0);
        acc0 = fmaf(x0.z, a4.z, acc0); acc0 = fmaf(x0.w, a4.w, acc0);
        acc1 = fmaf(x1.x, a4.x, acc1); acc1 = fmaf(x1.y, a4.y, acc1);
        acc1 = fmaf(x1.z, a4.z, acc1); acc1 = fmaf(x1.w, a4.w, acc1);
        acc2 = fmaf(x2.x, a4.x, acc2); acc2 = fmaf(x2.y, a4.y, acc2);
        acc2 = fmaf(x2.z, a4.z, acc2); acc2 = fmaf(x2.w, a4.w, acc2);
    }
    float bl0 = bs[lane], bl1 = bs[lane + 16], bl2 = bs[lane + 32];
    float smx = gsum(acc0 * acc0 + acc1 * acc1 + acc2 * acc2);
    float xyr = gsum(acc0 * bl0 + acc1 * bl1 + acc2 * bl2);
    float bn2 = gsum(bl0 * bl0 + bl1 * bl1 + bl2 * bl2);

    float mxnr = sqrtf(smx);
    float mxn = fmaxf(mxnr, F_EPS);
    float tt = fast_tanh(__fdividef(mxn, xn) * fast_atanh(xn));
    float sc = __fdividef(tt, mxn);
    float rn = mxnr * sc;
    if (rn > MAXNORM) sc *= MAXNORM / fmaxf(rn, F_EPS);

    float bn  = fmaxf(sqrtf(bn2), F_EPS);
    float ebs = __fdividef(fast_tanh(bn), bn);
    float y2  = ebs * ebs * bn2;

    float x2v = sc * sc * smx;
    float xy = sc * ebs * xyr;
    float c1 = 1.0f + 2.0f * xy + y2;
    float c2 = 1.0f - x2v;
    float dn3 = 1.0f / fmaxf(1.0f + 2.0f * xy + x2v * y2, F_EPS);

    float s3 = dn3 * dn3 * (c1 * c1 * sc * sc * smx
                            + 2.0f * c1 * c2 * sc * ebs * xyr
                            + c2 * c2 * ebs * ebs * bn2);
    float nrm3 = sqrtf(s3);
    float fp = (nrm3 > MAXNORM) ? (MAXNORM / fmaxf(nrm3, F_EPS)) : 1.0f;

    float CA = c1 * sc * dn3 * fp;
    float CB = c2 * ebs * dn3 * fp;

    if (act) {
        float* orow = out + (size_t)i * D;
        orow[lane]      = fmaf(CA, acc0, CB * bl0);
        orow[lane + 16] = fmaf(CA, acc1, CB * bl1);
        orow[lane + 32] = fmaf(CA, acc2, CB * bl2);
    }
}

// ---------- fallback path (atomic scatter + standalone node) ----------
__global__ void k_init_atomic(float* __restrict__ den, float* __restrict__ num, int n)
{
    int i = blockIdx.x * blockDim.x + threadIdx.x;
    if (i >= n) return;
    den[i] = 0.0f;
    float4* nr = reinterpret_cast<float4*>(num) + (size_t)i * DQ;
    float4 z = make_float4(0.f, 0.f, 0.f, 0.f);
#pragma unroll
    for (int q = 0; q < DQ; ++q) nr[q] = z;
}

__global__ void k_edge_atomic(const float* __restrict__ x, const float* __restrict__ gam,
                              const int* __restrict__ src, const int* __restrict__ dst,
                              const float* __restrict__ w,
                              float* __restrict__ num, float* __restrict__ den, int E)
{
    long long t = (long long)blockIdx.x * blockDim.x + threadIdx.x;
    int e = (int)(t / DQ);
    if (e >= E) return;
    int part = (int)(t % DQ);
    int s = src[e];
    int d = dst[e];
    float we = w[e];
    float g  = gam[s];
    float4 xv = reinterpret_cast<const float4*>(x)[(size_t)s * DQ + part];
    float c = we * g;
    float* np_ = num + (size_t)d * D + part * 4;
    atomicAdd(np_ + 0, c * xv.x);
    atomicAdd(np_ + 1, c * xv.y);
    atomicAdd(np_ + 2, c * xv.z);
    atomicAdd(np_ + 3, c * xv.w);
    if (part == 0) atomicAdd(den + d, fabsf(we) * (g - 1.0f));
}

__global__ __launch_bounds__(256) void k_node_fb(
    float* __restrict__ out,
    const float* __restrict__ den,
    const float* __restrict__ h_init,
    const float* __restrict__ Wm,
    const float* __restrict__ bias, int n)
{
    __shared__ float Ws[D * WSTR];
    __shared__ float bs[D];
    __shared__ float aLds[NPB][WSTR];
    int t = threadIdx.x;
    for (int k = t; k < D * D; k += 256) Ws[(k / D) * WSTR + (k % D)] = Wm[k];
    if (t < D) bs[t] = bias[t];
    __syncthreads();

    int grp = t >> 4;
    int lane = t & 15;
    int i = blockIdx.x * NPB + grp;
    bool act = (i < n);

    auto gsum = [](float v) {
        v += __shfl_xor(v, 1, 16);
        v += __shfl_xor(v, 2, 16);
        v += __shfl_xor(v, 4, 16);
        v += __shfl_xor(v, 8, 16);
        return v;
    };
    auto hmp_scale = [](float s) {
        float nrm = sqrtf(s);
        float ncl = fmaxf(nrm, F_EPS);
        float m = fminf(ncl, 1.0f - 1e-7f);
        float sc = __fdividef(__fdividef(m, ncl),
                              1.0f + sqrtf(fmaxf(1.0f - m * m, 0.0f)));
        float rn = nrm * sc;
        if (rn > MAXNORM) sc *= MAXNORM / fmaxf(rn, F_EPS);
        return sc;
    };

    float a0 = 0.f, a1 = 0.f, a2 = 0.f;
    if (act) {
        float dinv = 1.0f / clampabs(den[i]);
        const float* nr = out + (size_t)i * D;
        a0 = nr[lane] * dinv;
        a1 = nr[lane + 16] * dinv;
        a2 = nr[lane + 32] * dinv;
    }
    float s1 = gsum(a0 * a0 + a1 * a1 + a2 * a2);
    float sc1 = hmp_scale(s1);
    a0 *= sc1; a1 *= sc1; a2 *= sc1;
    float sa = s1 * sc1 * sc1;

    float s2, sc2;
    {
        float b0 = 0.f, b1 = 0.f, b2 = 0.f;
        if (act) {
            const float* hr = h_init + (size_t)i * D;
            b0 = hr[lane];
            b1 = hr[lane + 16];
            b2 = hr[lane + 32];
        }
        float sb = gsum(b0 * b0 + b1 * b1 + b2 * b2);
        float ga = 2.0f / fmaxf(1.0f - sa, F_EPS);
        float gb = 2.0f / fmaxf(1.0f - sb, F_EPS);
        const float wa = 0.9f, wb = 0.1f;
        float dinv = 1.0f / clampabs(wa * (ga - 1.0f) + wb * (gb - 1.0f));
        float ca = wa * ga * dinv, cb = wb * gb * dinv;
        a0 = ca * a0 + cb * b0;
        a1 = ca * a1 + cb * b1;
        a2 = ca * a2 + cb * b2;
        s2 = gsum(a0 * a0 + a1 * a1 + a2 * a2);
        sc2 = hmp_scale(s2);
        a0 *= sc2; a1 *= sc2; a2 *= sc2;
    }
    float xn = fmaxf(sqrtf(s2) * sc2, F_EPS);

    aLds[grp][lane]      = a0;
    aLds[grp][lane + 16] = a1;
    aLds[grp][lane + 32] = a2;
    __syncthreads();

    const float4* av4 = reinterpret_cast<const float4*>(&aLds[grp][0]);
    const float4* w04 = reinterpret_cast<const float4*>(&Ws[lane * WSTR]);
    const float4* w14 = reinterpret_cast<const float4*>(&Ws[(lane + 16) * WSTR]);
    const float4* w24 = reinterpret_cast<const float4*>(&Ws[(lane + 32) * WSTR]);
    float acc0 = 0.f, acc1 = 0.f, acc2 = 0.f;
#pragma unroll
    for (int kq = 0; kq < DQ; ++kq) {
        float4 a4 = av4[kq];
        float4 x0 = w04[kq];
        float4 x1 = w14[kq];
        float4 x2 = w24[kq];
        acc0 = fmaf(x0.x, a4.x, acc0); acc0 = fmaf(x0.y, a4.y, acc0);
        acc0 = fmaf(x0.z, a4.z, acc0); acc0 = fmaf(x0.w, a4.w, acc0);
        acc1 = fmaf(x1.x, a4.x, acc1); acc1 = fmaf(x1.y, a4.y, acc1);
        acc1 = fmaf(x1.z, a4.z, acc1); acc1 = fmaf(x1.w, a4.w, acc1);
        acc2 = fmaf(x2.x, a4.x, acc2); acc2 = fmaf(x2.y, a4.y, acc2);
        acc2 = fmaf(x2.z, a4.z, acc2); acc2 = fmaf(x2.w, a4.w, acc2);
    }
    float bl0 = bs[lane], bl1 = bs[lane + 16], bl2 = bs[lane + 32];
    float smx = gsum(acc0 * acc0 + acc1 * acc1 + acc2 * acc2);
    float xyr = gsum(acc0 * bl0 + acc1 * bl1 + acc2 * bl2);
    float bn2 = gsum(bl0 * bl0 + bl1 * bl1 + bl2 * bl2);

    float mxnr = sqrtf(smx);
    float mxn = fmaxf(mxnr, F_EPS);
    float tt = fast_tanh(__fdividef(mxn, xn) * fast_atanh(xn));
    float sc = __fdividef(tt, mxn);
    float rn = mxnr * sc;
    if (rn > MAXNORM) sc *= MAXNORM / fmaxf(rn, F_EPS);

    float bn  = fmaxf(sqrtf(bn2), F_EPS);
    float ebs = __fdividef(fast_tanh(bn), bn);
    float y2  = ebs * ebs * bn2;

    float x2v = sc * sc * smx;
    float xy = sc * ebs * xyr;
    float c1 = 1.0f + 2.0f * xy + y2;
    float c2 = 1.0f - x2v;
    float dn3 = 1.0f / fmaxf(1.0f + 2.0f * xy + x2v * y2, F_EPS);

    float s3 = dn3 * dn3 * (c1 * c1 * sc * sc * smx
                            + 2.0f * c1 * c2 * sc * ebs * xyr
                            + c2 * c2 * ebs * ebs * bn2);
    float nrm3 = sqrtf(s3);
    float fp = (nrm3 > MAXNORM) ? (MAXNORM / fmaxf(nrm3, F_EPS)) : 1.0f;

    float CA = c1 * sc * dn3 * fp;
    float CB = c2 * ebs * dn3 * fp;

    if (act) {
        float* orow = out + (size_t)i * D;
        orow[lane]      = fmaf(CA, acc0, CB * bl0);
        orow[lane + 16] = fmaf(CA, acc1, CB * bl1);
        orow[lane + 32] = fmaf(CA, acc2, CB * bl2);
    }
}

extern "C" void kernel_launch(void* const* d_in, const int* in_sizes, int n_in,
                              void* d_out, int out_size, void* d_ws, size_t ws_size,
                              hipStream_t stream)
{
    const float* x      = (const float*)d_in[0];
    const float* h_init = (const float*)d_in[1];
    const float* edge_w = (const float*)d_in[2];
    const float* W      = (const float*)d_in[3];
    const float* bias   = (const float*)d_in[4];
    const int*   esrc   = (const int*)d_in[5];
    const int*   edst   = (const int*)d_in[6];
    float* out = (float*)d_out;

    int n = in_sizes[0] / D;
    int E = in_sizes[2];
    int nb = (n + SPAN - 1) >> SHIFT;

    // ws layout
    char* p = (char*)d_ws;
    float* gam    = (float*)p;             p += (size_t)n * 4;
    float* den    = (float*)p;             p += (size_t)n * 4;
    int*   ghist  = (int*)p;               p += (size_t)nb * 4;
    int*   gstart = (int*)p;               p += (size_t)(nb + 1) * 4;
    int*   gcur   = (int*)p;               p += (size_t)nb * 4;
    int*   starts = (int*)p;               p += (size_t)(n + 1) * 4;
    p = (char*)(((uintptr_t)p + 15) & ~(uintptr_t)15);   // align 16
    int2*  seg    = (int2*)p;              p += (size_t)E * 8;
    int2*  seg2   = (int2*)p;              p += (size_t)E * 8;
    size_t need1 = (size_t)(p - (char*)d_ws);
    ushort4* ybf = (ushort4*)seg;          // aliases seg (dead after k_sortb)
    bool ybf_fits = ((size_t)E * 8 >= (size_t)n * YROW * 8);

    k_gamma<<<(n + 255) / 256, 256, 0, stream>>>(x, gam, ghist, n, nb);

    bool shape_ok = (nb <= 1024) && (n < (1 << 24));
    if (shape_ok && ybf_fits && need1 <= ws_size) {
        int pb = (E + PCH - 1) / PCH;
        k_hist<<<pb, PTH, 0, stream>>>(edst, ghist, E, nb);
        k_scanb<<<1, 1024, 0, stream>>>(ghist, gstart, gcur, nb, E);
        k_part<<<pb, PTH, 0, stream>>>(esrc, edst, edge_w, gcur, seg, E, nb);
        k_sortb<<<nb, 256, 0, stream>>>(seg, gstart, starts, seg2, n, E);
        long long pt = (long long)n * YROW;
        k_prep<<<(int)((pt + 255) / 256), 256, 0, stream>>>(x, gam, ybf, n);
        k_fuse<<<(n + NPB - 1) / NPB, 256, 0, stream>>>(
            ybf, starts, seg2, h_init, W, bias, out, n, E);
    } else {
        k_init_atomic<<<(n + 255) / 256, 256, 0, stream>>>(den, out, n);
        long long tot = (long long)E * DQ;
        k_edge_atomic<<<(int)((tot + 255) / 256), 256, 0, stream>>>(x, gam, esrc, edst, edge_w, out, den, E);
        k_node_fb<<<(n + NPB - 1) / NPB, 256, 0, stream>>>(out, den, h_init, W, bias, n);
    }
}

// Round 17
// 138.556 us; speedup vs baseline: 1.1861x; 1.0445x over previous
//
#include <hip/hip_runtime.h>
#include <math.h>

#define D  48
#define DQ 12        // D/4
#define SPAN 128     // nodes per bucket
#define SHIFT 7      // log2(SPAN)
#define PCH  8192    // edges per hist/partition block
#define PTH  512     // threads for hist/part
#define NPB  16      // nodes per k_fuse block (16 threads/node)
#define WSTR 52      // LDS row stride (16B-aligned, low-conflict float4 reads)
#define YROW 16      // ybf row: 12 x ushort4 bf16(g*x) + slot12 (g-1 fp32) + pad to 128B (line-aligned)

constexpr float F_EPS   = 1e-15f;
constexpr float MAXNORM = 1.0f - 1e-5f;

__device__ __forceinline__ float clampabs(float x) {
    return (x >= 0.0f) ? fmaxf(x, 1e-10f) : fminf(x, -1e-10f);
}

__device__ __forceinline__ unsigned short f2bf(float f) {
    unsigned u = __float_as_uint(f);
    u += 0x7FFFu + ((u >> 16) & 1u);
    return (unsigned short)(u >> 16);
}

__device__ __forceinline__ float bf2f(unsigned short u) {
    return __uint_as_float(((unsigned)u) << 16);
}

__device__ __forceinline__ float gm1f(ushort4 a) {   // fp32 packed in .x/.y
    return __uint_as_float((unsigned)a.x | ((unsigned)a.y << 16));
}

// fast tanh for x>=0 via hw exp (overflow-safe); fast atanh for 0<=x<1
__device__ __forceinline__ float fast_tanh(float x) {
    float e = __expf(2.0f * x);
    return 1.0f - __fdividef(2.0f, e + 1.0f);
}
__device__ __forceinline__ float fast_atanh(float x) {
    x = fminf(x, 1.0f - 1e-7f);
    return 0.5f * __logf(__fdividef(1.0f + x, 1.0f - x));
}

// ---------- per-node gamma + zero bucket histogram ----------
__global__ void k_gamma(const float* __restrict__ x, float* __restrict__ gam,
                        int* __restrict__ ghist, int n, int nb)
{
    int i = blockIdx.x * blockDim.x + threadIdx.x;
    if (i < nb) ghist[i] = 0;
    if (i >= n) return;
    const float4* xr = reinterpret_cast<const float4*>(x) + (size_t)i * DQ;
    float s = 0.0f;
#pragma unroll
    for (int q = 0; q < DQ; ++q) {
        float4 v = xr[q];
        s += v.x * v.x + v.y * v.y + v.z * v.z + v.w * v.w;
    }
    gam[i] = 2.0f / fmaxf(1.0f - s, F_EPS);
}

// ---------- bucket histogram (LDS-staged) ----------
__global__ __launch_bounds__(PTH) void k_hist(const int* __restrict__ dst,
                                              int* __restrict__ ghist, int E, int nb)
{
    __shared__ int h[1024];
    int t = threadIdx.x;
    for (int i = t; i < 1024; i += PTH) h[i] = 0;
    __syncthreads();
    int base = blockIdx.x * PCH;
#pragma unroll 4
    for (int k = 0; k < PCH / PTH; ++k) {
        int i = base + k * PTH + t;
        if (i < E) {
            unsigned b = ((unsigned)dst[i]) >> SHIFT;
            if (b < 1024u) atomicAdd(&h[b], 1);
        }
    }
    __syncthreads();
    for (int i = t; i < nb; i += PTH) {
        int c = h[i];
        if (c) atomicAdd(&ghist[i], c);
    }
}

// ---------- exclusive scan of bucket counts (single block, nb <= 1024) ----------
__global__ __launch_bounds__(1024) void k_scanb(const int* __restrict__ ghist,
                                                int* __restrict__ gstart,
                                                int* __restrict__ gcur, int nb, int E)
{
    __shared__ int sh[1024];
    int t = threadIdx.x;
    int v = (t < nb) ? ghist[t] : 0;
    sh[t] = v;
    __syncthreads();
    for (int off = 1; off < 1024; off <<= 1) {
        int a = sh[t];
        int b = (t >= off) ? sh[t - off] : 0;
        __syncthreads();
        sh[t] = a + b;
        __syncthreads();
    }
    if (t < nb) { int s = sh[t] - v; gstart[t] = s; gcur[t] = s; }
    if (t == 0) gstart[nb] = E;
}

// ---------- partition (pure streaming — no gam read; fp32 w in record) ----------
__global__ __launch_bounds__(PTH) void k_part(const int* __restrict__ src,
                                              const int* __restrict__ dst,
                                              const float* __restrict__ w,
                                              int* __restrict__ gcur,
                                              int2* __restrict__ seg, int E, int nb)
{
    __shared__ int hist[1024];
    __shared__ int base_[1024];
    __shared__ int lcur[1024];
    int t = threadIdx.x;
    for (int i = t; i < 1024; i += PTH) { hist[i] = 0; base_[i] = 0; lcur[i] = 0; }
    __syncthreads();
    int b0 = blockIdx.x * PCH;
#pragma unroll 4
    for (int k = 0; k < PCH / PTH; ++k) {
        int i = b0 + k * PTH + t;
        if (i < E) {
            unsigned b = ((unsigned)dst[i]) >> SHIFT;
            if (b < 1024u) atomicAdd(&hist[b], 1);
        }
    }
    __syncthreads();
    for (int i = t; i < nb; i += PTH) {
        int c = hist[i];
        if (c) base_[i] = atomicAdd(&gcur[i], c);
    }
    __syncthreads();
#pragma unroll 4
    for (int k = 0; k < PCH / PTH; ++k) {
        int i = b0 + k * PTH + t;
        if (i < E) {
            int d = dst[i];
            unsigned b = ((unsigned)d) >> SHIFT;
            if (b < 1024u) {
                int pos = base_[b] + atomicAdd(&lcur[b], 1);
                if (pos >= 0 && pos < E) {
                    int2 r;
                    r.x = ((d & (SPAN - 1)) << 24) | (src[i] & 0xFFFFFF);
                    r.y = __float_as_int(w[i]);
                    seg[pos] = r;
                }
            }
        }
    }
}

// ---------- per-bucket LDS counting sort -> exact per-node order + starts ----------
__global__ __launch_bounds__(256) void k_sortb(
    const int2* __restrict__ seg, const int* __restrict__ gstart,
    int* __restrict__ starts, int2* __restrict__ seg2, int n, int E)
{
    __shared__ int hist[SPAN];
    __shared__ int sb[SPAN];
    __shared__ int cur[SPAN];
    int b = blockIdx.x;
    int t = threadIdx.x;
    if (b == 0 && t == 0) starts[n] = E;
    int segL = gstart[b], segR = gstart[b + 1];
    if (segL < 0) segL = 0;
    if (segR > E) segR = E;
    if (t < SPAN) hist[t] = 0;
    __syncthreads();
    {
        int j = segL + t;
        for (; j + 768 < segR; j += 1024) {
            unsigned d0 = ((unsigned)seg[j      ].x) >> 24;
            unsigned d1 = ((unsigned)seg[j + 256].x) >> 24;
            unsigned d2 = ((unsigned)seg[j + 512].x) >> 24;
            unsigned d3 = ((unsigned)seg[j + 768].x) >> 24;
            atomicAdd(&hist[d0], 1);
            atomicAdd(&hist[d1], 1);
            atomicAdd(&hist[d2], 1);
            atomicAdd(&hist[d3], 1);
        }
        for (; j < segR; j += 256) {
            unsigned dl = ((unsigned)seg[j].x) >> 24;
            atomicAdd(&hist[dl], 1);
        }
    }
    __syncthreads();
    if (t < SPAN) sb[t] = hist[t];
    __syncthreads();
    for (int off = 1; off < SPAN; off <<= 1) {
        int a = 0;
        if (t < SPAN) { a = sb[t]; if (t >= off) a += sb[t - off]; }
        __syncthreads();
        if (t < SPAN) sb[t] = a;
        __syncthreads();
    }
    if (t < SPAN) {
        int ls = sb[t] - hist[t];
        cur[t] = segL + ls;
        int node = b * SPAN + t;
        if (node < n) starts[node] = segL + ls;
    }
    __syncthreads();
    {
        int j = segL + t;
        for (; j + 768 < segR; j += 1024) {
            int2 r0 = seg[j      ];
            int2 r1 = seg[j + 256];
            int2 r2 = seg[j + 512];
            int2 r3 = seg[j + 768];
            int p0 = atomicAdd(&cur[((unsigned)r0.x) >> 24], 1);
            int p1 = atomicAdd(&cur[((unsigned)r1.x) >> 24], 1);
            int p2 = atomicAdd(&cur[((unsigned)r2.x) >> 24], 1);
            int p3 = atomicAdd(&cur[((unsigned)r3.x) >> 24], 1);
            if (p0 >= 0 && p0 < E) seg2[p0] = make_int2(r0.x & 0xFFFFFF, r0.y);
            if (p1 >= 0 && p1 < E) seg2[p1] = make_int2(r1.x & 0xFFFFFF, r1.y);
            if (p2 >= 0 && p2 < E) seg2[p2] = make_int2(r2.x & 0xFFFFFF, r2.y);
            if (p3 >= 0 && p3 < E) seg2[p3] = make_int2(r3.x & 0xFFFFFF, r3.y);
        }
        for (; j < segR; j += 256) {
            int2 r = seg[j];
            int pos = atomicAdd(&cur[((unsigned)r.x) >> 24], 1);
            if (pos >= 0 && pos < E) seg2[pos] = make_int2(r.x & 0xFFFFFF, r.y);
        }
    }
}

// ---------- k_prep: 128B-aligned ybf rows: 12x bf16(g*x) + fp32(g-1) + pad ----------
__global__ __launch_bounds__(256) void k_prep(const float* __restrict__ x,
                                              const float* __restrict__ gam,
                                              ushort4* __restrict__ ybf, int n)
{
    long long t = (long long)blockIdx.x * blockDim.x + threadIdx.x;
    int node = (int)(t / YROW);
    if (node >= n) return;
    int slot = (int)(t % YROW);
    float g = gam[node];
    ushort4 o;
    if (slot < 12) {
        float4 v = reinterpret_cast<const float4*>(x)[(size_t)node * DQ + slot];
        o.x = f2bf(v.x * g);
        o.y = f2bf(v.y * g);
        o.z = f2bf(v.z * g);
        o.w = f2bf(v.w * g);
    } else if (slot == 12) {
        unsigned u = __float_as_uint(g - 1.0f);
        o.x = (unsigned short)(u & 0xFFFFu);
        o.y = (unsigned short)(u >> 16);
        o.z = 0; o.w = 0;
    } else {
        o.x = 0; o.y = 0; o.z = 0; o.w = 0;   // pad
    }
    ybf[(size_t)node * YROW + slot] = o;
}

// ---------- fused gather + node math: 16 lanes per node ----------
__global__ __launch_bounds__(256) void k_fuse(
    const ushort4* __restrict__ ybf,
    const int* __restrict__ starts,
    const int2* __restrict__ srec,
    const float* __restrict__ h_init,
    const float* __restrict__ Wm,
    const float* __restrict__ bias,
    float* __restrict__ out, int n, int E)
{
    __shared__ float Ws[D * WSTR];
    __shared__ float bs[D];
    __shared__ float aLds[NPB][WSTR];
    int t = threadIdx.x;
    for (int k = t; k < D * D; k += 256) Ws[(k / D) * WSTR + (k % D)] = Wm[k];
    if (t < D) bs[t] = bias[t];

    int grp = t >> 4;
    int lane = t & 15;
    int i = blockIdx.x * NPB + grp;
    bool act = (i < n);

    auto gsum = [](float v) {
        v += __shfl_xor(v, 1, 16);
        v += __shfl_xor(v, 2, 16);
        v += __shfl_xor(v, 4, 16);
        v += __shfl_xor(v, 8, 16);
        return v;
    };
    auto hmp_scale = [](float s) {     // tanh(0.5*atanh(m))/m with project
        float nrm = sqrtf(s);
        float ncl = fmaxf(nrm, F_EPS);
        float m = fminf(ncl, 1.0f - 1e-7f);
        float sc = __fdividef(__fdividef(m, ncl),
                              1.0f + sqrtf(fmaxf(1.0f - m * m, 0.0f)));
        float rn = nrm * sc;
        if (rn > MAXNORM) sc *= MAXNORM / fmaxf(rn, F_EPS);
        return sc;
    };

    // ---- gather phase: lanes 0-11 num fragments, lane 12 den (gamma slot)
    int j0 = 0, j1 = 0;
    if (act) {
        j0 = starts[i]; j1 = starts[i + 1];
        if (j0 < 0) j0 = 0;
        if (j1 > E) j1 = E;
    }
    int pp = (lane < 12) ? lane : 12;
    float4 acc = make_float4(0.f, 0.f, 0.f, 0.f);
    float dacc = 0.f;
    int j = j0;
    for (; j + 3 < j1; j += 4) {
        int2 r0 = srec[j];
        int2 r1 = srec[j + 1];
        int2 r2 = srec[j + 2];
        int2 r3 = srec[j + 3];
        ushort4 a0 = ybf[(size_t)r0.x * YROW + pp];
        ushort4 a1 = ybf[(size_t)r1.x * YROW + pp];
        ushort4 a2 = ybf[(size_t)r2.x * YROW + pp];
        ushort4 a3 = ybf[(size_t)r3.x * YROW + pp];
        float w0 = __int_as_float(r0.y);
        float w1 = __int_as_float(r1.y);
        float w2 = __int_as_float(r2.y);
        float w3 = __int_as_float(r3.y);
        if (lane < 12) {
            acc.x = fmaf(w0, bf2f(a0.x), acc.x);
            acc.y = fmaf(w0, bf2f(a0.y), acc.y);
            acc.z = fmaf(w0, bf2f(a0.z), acc.z);
            acc.w = fmaf(w0, bf2f(a0.w), acc.w);
            acc.x = fmaf(w1, bf2f(a1.x), acc.x);
            acc.y = fmaf(w1, bf2f(a1.y), acc.y);
            acc.z = fmaf(w1, bf2f(a1.z), acc.z);
            acc.w = fmaf(w1, bf2f(a1.w), acc.w);
            acc.x = fmaf(w2, bf2f(a2.x), acc.x);
            acc.y = fmaf(w2, bf2f(a2.y), acc.y);
            acc.z = fmaf(w2, bf2f(a2.z), acc.z);
            acc.w = fmaf(w2, bf2f(a2.w), acc.w);
            acc.x = fmaf(w3, bf2f(a3.x), acc.x);
            acc.y = fmaf(w3, bf2f(a3.y), acc.y);
            acc.z = fmaf(w3, bf2f(a3.z), acc.z);
            acc.w = fmaf(w3, bf2f(a3.w), acc.w);
        } else if (lane == 12) {
            dacc += fabsf(w0) * gm1f(a0) + fabsf(w1) * gm1f(a1)
                  + fabsf(w2) * gm1f(a2) + fabsf(w3) * gm1f(a3);
        }
    }
    for (; j < j1; ++j) {
        int2 r0 = srec[j];
        ushort4 a0 = ybf[(size_t)r0.x * YROW + pp];
        float w0 = __int_as_float(r0.y);
        if (lane < 12) {
            acc.x = fmaf(w0, bf2f(a0.x), acc.x);
            acc.y = fmaf(w0, bf2f(a0.y), acc.y);
            acc.z = fmaf(w0, bf2f(a0.z), acc.z);
            acc.w = fmaf(w0, bf2f(a0.w), acc.w);
        } else if (lane == 12) {
            dacc += fabsf(w0) * gm1f(a0);
        }
    }

    float dv = __shfl(dacc, 12, 16);           // broadcast den to group

    // redistribute num fragments (4p..4p+3) -> per-lane elems {l,l+16,l+32}
    if (lane < 12)
        reinterpret_cast<float4*>(&aLds[grp][0])[lane] = acc;
    __syncthreads();

    // ---- node math
    float dinv = 1.0f / clampabs(dv);
    float a0 = aLds[grp][lane]      * dinv;
    float a1 = aLds[grp][lane + 16] * dinv;
    float a2 = aLds[grp][lane + 32] * dinv;

    float s1 = gsum(a0 * a0 + a1 * a1 + a2 * a2);
    float sc1 = hmp_scale(s1);
    a0 *= sc1; a1 *= sc1; a2 *= sc1;
    float sa = s1 * sc1 * sc1;

    float s2, sc2;
    {
        float b0 = 0.f, b1 = 0.f, b2 = 0.f;
        if (act) {
            const float* hr = h_init + (size_t)i * D;
            b0 = hr[lane];
            b1 = hr[lane + 16];
            b2 = hr[lane + 32];
        }
        float sb = gsum(b0 * b0 + b1 * b1 + b2 * b2);
        float ga = 2.0f / fmaxf(1.0f - sa, F_EPS);
        float gb = 2.0f / fmaxf(1.0f - sb, F_EPS);
        const float wa = 0.9f, wb = 0.1f;
        float dinv2 = 1.0f / clampabs(wa * (ga - 1.0f) + wb * (gb - 1.0f));
        float ca = wa * ga * dinv2, cb = wb * gb * dinv2;
        a0 = ca * a0 + cb * b0;
        a1 = ca * a1 + cb * b1;
        a2 = ca * a2 + cb * b2;
        s2 = gsum(a0 * a0 + a1 * a1 + a2 * a2);
        sc2 = hmp_scale(s2);
        a0 *= sc2; a1 *= sc2; a2 *= sc2;
    }
    float xn = fmaxf(sqrtf(s2) * sc2, F_EPS);

    // restage projected a for the float4 matvec
    aLds[grp][lane]      = a0;
    aLds[grp][lane + 16] = a1;
    aLds[grp][lane + 32] = a2;
    __syncthreads();

    const float4* av4 = reinterpret_cast<const float4*>(&aLds[grp][0]);
    const float4* w04 = reinterpret_cast<const float4*>(&Ws[lane * WSTR]);
    const float4* w14 = reinterpret_cast<const float4*>(&Ws[(lane + 16) * WSTR]);
    const float4* w24 = reinterpret_cast<const float4*>(&Ws[(lane + 32) * WSTR]);
    float acc0 = 0.f, acc1 = 0.f, acc2 = 0.f;
#pragma unroll
    for (int kq = 0; kq < DQ; ++kq) {
        float4 a4 = av4[kq];
        float4 x0 = w04[kq];
        float4 x1 = w14[kq];
        float4 x2 = w24[kq];
        acc0 = fmaf(x0.x, a4.x, acc0); acc0 = fmaf(x0.y, a4.y, acc0);
        acc0 = fmaf(x0.z, a4.z, acc0); acc0 = fmaf(x0.w, a4.w, acc0);
        acc1 = fmaf(x1.x, a4.x, acc1); acc1 = fmaf(x1.y, a4.y, acc1);
        acc1 = fmaf(x1.z, a4.z, acc1); acc1 = fmaf(x1.w, a4.w, acc1);
        acc2 = fmaf(x2.x, a4.x, acc2); acc2 = fmaf(x2.y, a4.y, acc2);
        acc2 = fmaf(x2.z, a4.z, acc2); acc2 = fmaf(x2.w, a4.w, acc2);
    }
    float bl0 = bs[lane], bl1 = bs[lane + 16], bl2 = bs[lane + 32];
    float smx = gsum(acc0 * acc0 + acc1 * acc1 + acc2 * acc2);
    float xyr = gsum(acc0 * bl0 + acc1 * bl1 + acc2 * bl2);
    float bn2 = gsum(bl0 * bl0 + bl1 * bl1 + bl2 * bl2);

    float mxnr = sqrtf(smx);
    float mxn = fmaxf(mxnr, F_EPS);
    float tt = fast_tanh(__fdividef(mxn, xn) * fast_atanh(xn));
    float sc = __fdividef(tt, mxn);
    float rn = mxnr * sc;
    if (rn > MAXNORM) sc *= MAXNORM / fmaxf(rn, F_EPS);

    float bn  = fmaxf(sqrtf(bn2), F_EPS);
    float ebs = __fdividef(fast_tanh(bn), bn);
    float y2  = ebs * ebs * bn2;

    float x2v = sc * sc * smx;
    float xy = sc * ebs * xyr;
    float c1 = 1.0f + 2.0f * xy + y2;
    float c2 = 1.0f - x2v;
    float dn3 = 1.0f / fmaxf(1.0f + 2.0f * xy + x2v * y2, F_EPS);

    float s3 = dn3 * dn3 * (c1 * c1 * sc * sc * smx
                            + 2.0f * c1 * c2 * sc * ebs * xyr
                            + c2 * c2 * ebs * ebs * bn2);
    float nrm3 = sqrtf(s3);
    float fp = (nrm3 > MAXNORM) ? (MAXNORM / fmaxf(nrm3, F_EPS)) : 1.0f;

    float CA = c1 * sc * dn3 * fp;
    float CB = c2 * ebs * dn3 * fp;

    if (act) {
        float* orow = out + (size_t)i * D;
        orow[lane]      = fmaf(CA, acc0, CB * bl0);
        orow[lane + 16] = fmaf(CA, acc1, CB * bl1);
        orow[lane + 32] = fmaf(CA, acc2, CB * bl2);
    }
}

// ---------- fallback path (atomic scatter + standalone node) ----------
__global__ void k_init_atomic(float* __restrict__ den, float* __restrict__ num, int n)
{
    int i = blockIdx.x * blockDim.x + threadIdx.x;
    if (i >= n) return;
    den[i] = 0.0f;
    float4* nr = reinterpret_cast<float4*>(num) + (size_t)i * DQ;
    float4 z = make_float4(0.f, 0.f, 0.f, 0.f);
#pragma unroll
    for (int q = 0; q < DQ; ++q) nr[q] = z;
}

__global__ void k_edge_atomic(const float* __restrict__ x, const float* __restrict__ gam,
                              const int* __restrict__ src, const int* __restrict__ dst,
                              const float* __restrict__ w,
                              float* __restrict__ num, float* __restrict__ den, int E)
{
    long long t = (long long)blockIdx.x * blockDim.x + threadIdx.x;
    int e = (int)(t / DQ);
    if (e >= E) return;
    int part = (int)(t % DQ);
    int s = src[e];
    int d = dst[e];
    float we = w[e];
    float g  = gam[s];
    float4 xv = reinterpret_cast<const float4*>(x)[(size_t)s * DQ + part];
    float c = we * g;
    float* np_ = num + (size_t)d * D + part * 4;
    atomicAdd(np_ + 0, c * xv.x);
    atomicAdd(np_ + 1, c * xv.y);
    atomicAdd(np_ + 2, c * xv.z);
    atomicAdd(np_ + 3, c * xv.w);
    if (part == 0) atomicAdd(den + d, fabsf(we) * (g - 1.0f));
}

__global__ __launch_bounds__(256) void k_node_fb(
    float* __restrict__ out,
    const float* __restrict__ den,
    const float* __restrict__ h_init,
    const float* __restrict__ Wm,
    const float* __restrict__ bias, int n)
{
    __shared__ float Ws[D * WSTR];
    __shared__ float bs[D];
    __shared__ float aLds[NPB][WSTR];
    int t = threadIdx.x;
    for (int k = t; k < D * D; k += 256) Ws[(k / D) * WSTR + (k % D)] = Wm[k];
    if (t < D) bs[t] = bias[t];
    __syncthreads();

    int grp = t >> 4;
    int lane = t & 15;
    int i = blockIdx.x * NPB + grp;
    bool act = (i < n);

    auto gsum = [](float v) {
        v += __shfl_xor(v, 1, 16);
        v += __shfl_xor(v, 2, 16);
        v += __shfl_xor(v, 4, 16);
        v += __shfl_xor(v, 8, 16);
        return v;
    };
    auto hmp_scale = [](float s) {
        float nrm = sqrtf(s);
        float ncl = fmaxf(nrm, F_EPS);
        float m = fminf(ncl, 1.0f - 1e-7f);
        float sc = __fdividef(__fdividef(m, ncl),
                              1.0f + sqrtf(fmaxf(1.0f - m * m, 0.0f)));
        float rn = nrm * sc;
        if (rn > MAXNORM) sc *= MAXNORM / fmaxf(rn, F_EPS);
        return sc;
    };

    float a0 = 0.f, a1 = 0.f, a2 = 0.f;
    if (act) {
        float dinv = 1.0f / clampabs(den[i]);
        const float* nr = out + (size_t)i * D;
        a0 = nr[lane] * dinv;
        a1 = nr[lane + 16] * dinv;
        a2 = nr[lane + 32] * dinv;
    }
    float s1 = gsum(a0 * a0 + a1 * a1 + a2 * a2);
    float sc1 = hmp_scale(s1);
    a0 *= sc1; a1 *= sc1; a2 *= sc1;
    float sa = s1 * sc1 * sc1;

    float s2, sc2;
    {
        float b0 = 0.f, b1 = 0.f, b2 = 0.f;
        if (act) {
            const float* hr = h_init + (size_t)i * D;
            b0 = hr[lane];
            b1 = hr[lane + 16];
            b2 = hr[lane + 32];
        }
        float sb = gsum(b0 * b0 + b1 * b1 + b2 * b2);
        float ga = 2.0f / fmaxf(1.0f - sa, F_EPS);
        float gb = 2.0f / fmaxf(1.0f - sb, F_EPS);
        const float wa = 0.9f, wb = 0.1f;
        float dinv = 1.0f / clampabs(wa * (ga - 1.0f) + wb * (gb - 1.0f));
        float ca = wa * ga * dinv, cb = wb * gb * dinv;
        a0 = ca * a0 + cb * b0;
        a1 = ca * a1 + cb * b1;
        a2 = ca * a2 + cb * b2;
        s2 = gsum(a0 * a0 + a1 * a1 + a2 * a2);
        sc2 = hmp_scale(s2);
        a0 *= sc2; a1 *= sc2; a2 *= sc2;
    }
    float xn = fmaxf(sqrtf(s2) * sc2, F_EPS);

    aLds[grp][lane]      = a0;
    aLds[grp][lane + 16] = a1;
    aLds[grp][lane + 32] = a2;
    __syncthreads();

    const float4* av4 = reinterpret_cast<const float4*>(&aLds[grp][0]);
    const float4* w04 = reinterpret_cast<const float4*>(&Ws[lane * WSTR]);
    const float4* w14 = reinterpret_cast<const float4*>(&Ws[(lane + 16) * WSTR]);
    const float4* w24 = reinterpret_cast<const float4*>(&Ws[(lane + 32) * WSTR]);
    float acc0 = 0.f, acc1 = 0.f, acc2 = 0.f;
#pragma unroll
    for (int kq = 0; kq < DQ; ++kq) {
        float4 a4 = av4[kq];
        float4 x0 = w04[kq];
        float4 x1 = w14[kq];
        float4 x2 = w24[kq];
        acc0 = fmaf(x0.x, a4.x, acc0); acc0 = fmaf(x0.y, a4.y, acc0);
        acc0 = fmaf(x0.z, a4.z, acc0); acc0 = fmaf(x0.w, a4.w, acc0);
        acc1 = fmaf(x1.x, a4.x, acc1); acc1 = fmaf(x1.y, a4.y, acc1);
        acc1 = fmaf(x1.z, a4.z, acc1); acc1 = fmaf(x1.w, a4.w, acc1);
        acc2 = fmaf(x2.x, a4.x, acc2); acc2 = fmaf(x2.y, a4.y, acc2);
        acc2 = fmaf(x2.z, a4.z, acc2); acc2 = fmaf(x2.w, a4.w, acc2);
    }
    float bl0 = bs[lane], bl1 = bs[lane + 16], bl2 = bs[lane + 32];
    float smx = gsum(acc0 * acc0 + acc1 * acc1 + acc2 * acc2);
    float xyr = gsum(acc0 * bl0 + acc1 * bl1 + acc2 * bl2);
    float bn2 = gsum(bl0 * bl0 + bl1 * bl1 + bl2 * bl2);

    float mxnr = sqrtf(smx);
    float mxn = fmaxf(mxnr, F_EPS);
    float tt = fast_tanh(__fdividef(mxn, xn) * fast_atanh(xn));
    float sc = __fdividef(tt, mxn);
    float rn = mxnr * sc;
    if (rn > MAXNORM) sc *= MAXNORM / fmaxf(rn, F_EPS);

    float bn  = fmaxf(sqrtf(bn2), F_EPS);
    float ebs = __fdividef(fast_tanh(bn), bn);
    float y2  = ebs * ebs * bn2;

    float x2v = sc * sc * smx;
    float xy = sc * ebs * xyr;
    float c1 = 1.0f + 2.0f * xy + y2;
    float c2 = 1.0f - x2v;
    float dn3 = 1.0f / fmaxf(1.0f + 2.0f * xy + x2v * y2, F_EPS);

    float s3 = dn3 * dn3 * (c1 * c1 * sc * sc * smx
                            + 2.0f * c1 * c2 * sc * ebs * xyr
                            + c2 * c2 * ebs * ebs * bn2);
    float nrm3 = sqrtf(s3);
    float fp = (nrm3 > MAXNORM) ? (MAXNORM / fmaxf(nrm3, F_EPS)) : 1.0f;

    float CA = c1 * sc * dn3 * fp;
    float CB = c2 * ebs * dn3 * fp;

    if (act) {
        float* orow = out + (size_t)i * D;
        orow[lane]      = fmaf(CA, acc0, CB * bl0);
        orow[lane + 16] = fmaf(CA, acc1, CB * bl1);
        orow[lane + 32] = fmaf(CA, acc2, CB * bl2);
    }
}

extern "C" void kernel_launch(void* const* d_in, const int* in_sizes, int n_in,
                              void* d_out, int out_size, void* d_ws, size_t ws_size,
                              hipStream_t stream)
{
    const float* x      = (const float*)d_in[0];
    const float* h_init = (const float*)d_in[1];
    const float* edge_w = (const float*)d_in[2];
    const float* W      = (const float*)d_in[3];
    const float* bias   = (const float*)d_in[4];
    const int*   esrc   = (const int*)d_in[5];
    const int*   edst   = (const int*)d_in[6];
    float* out = (float*)d_out;

    int n = in_sizes[0] / D;
    int E = in_sizes[2];
    int nb = (n + SPAN - 1) >> SHIFT;

    // ws layout
    char* p = (char*)d_ws;
    float* gam    = (float*)p;             p += (size_t)n * 4;
    float* den    = (float*)p;             p += (size_t)n * 4;
    int*   ghist  = (int*)p;               p += (size_t)nb * 4;
    int*   gstart = (int*)p;               p += (size_t)(nb + 1) * 4;
    int*   gcur   = (int*)p;               p += (size_t)nb * 4;
    int*   starts = (int*)p;               p += (size_t)(n + 1) * 4;
    p = (char*)(((uintptr_t)p + 127) & ~(uintptr_t)127);  // align 128
    int2*  seg    = (int2*)p;              p += (size_t)E * 8;
    int2*  seg2   = (int2*)p;              p += (size_t)E * 8;
    size_t need1 = (size_t)(p - (char*)d_ws);
    ushort4* ybf = (ushort4*)seg;          // aliases seg (dead after k_sortb), 128B-aligned
    bool ybf_fits = ((size_t)E * 8 >= (size_t)n * YROW * 8);

    k_gamma<<<(n + 255) / 256, 256, 0, stream>>>(x, gam, ghist, n, nb);

    bool shape_ok = (nb <= 1024) && (n < (1 << 24));
    if (shape_ok && ybf_fits && need1 <= ws_size) {
        int pb = (E + PCH - 1) / PCH;
        k_hist<<<pb, PTH, 0, stream>>>(edst, ghist, E, nb);
        k_scanb<<<1, 1024, 0, stream>>>(ghist, gstart, gcur, nb, E);
        k_part<<<pb, PTH, 0, stream>>>(esrc, edst, edge_w, gcur, seg, E, nb);
        k_sortb<<<nb, 256, 0, stream>>>(seg, gstart, starts, seg2, n, E);
        long long pt = (long long)n * YROW;
        k_prep<<<(int)((pt + 255) / 256), 256, 0, stream>>>(x, gam, ybf, n);
        k_fuse<<<(n + NPB - 1) / NPB, 256, 0, stream>>>(
            ybf, starts, seg2, h_init, W, bias, out, n, E);
    } else {
        k_init_atomic<<<(n + 255) / 256, 256, 0, stream>>>(den, out, n);
        long long tot = (long long)E * DQ;
        k_edge_atomic<<<(int)((tot + 255) / 256), 256, 0, stream>>>(x, gam, esrc, edst, edge_w, out, den, E);
        k_node_fb<<<(n + NPB - 1) / NPB, 256, 0, stream>>>(out, den, h_init, W, bias, n);
    }
}